// Round 2
// baseline (476.459 us; speedup 1.0000x reference)
//
#include <hip/hip_runtime.h>
#include <hip/hip_bf16.h>

#define Dx 300

// float-offsets into ws
#define OFF_REP    0
#define OFF_DEP    307200      // holds exd = exp(0.4*(dep+b1))
#define OFF_HEAD   614400
#define OFF_ATTN   921600
// ushort arrays at U = (ushort*)(ws + 1228800): zero-padded
#define U_BASE     1228800
#define REPB       0           // [1024][320]
#define ATB        327680      // [1024][320]
#define WPACK      655360      // 4 x [320][320]: W1, W2, Wf1, Wf2 (contiguous)
#define WP1        655360
#define WP2        757760
#define WPF1       860160
#define WPF2       962560
// software grid-barrier state (zeroed by hipMemsetAsync before launch)
#define SYNC_FOFF  2000000     // float offset, 8 MB into ws — clear of all data

typedef __attribute__((ext_vector_type(8))) short short8;
typedef __attribute__((ext_vector_type(4))) float f32x4;

union S8 { unsigned int u[4]; unsigned short s[8]; short8 v; };

__device__ __forceinline__ float bf2f(unsigned short u) {
    union { unsigned int i; float f; } v; v.i = ((unsigned int)u) << 16; return v.f;
}
__device__ __forceinline__ unsigned short f2bf(float x) {   // round-half-up
    union { float f; unsigned int i; } u; u.f = x;
    return (unsigned short)((u.i + 0x8000u) >> 16);
}
__device__ __forceinline__ int detect_bf16(const void* w) {
    const unsigned short* u = (const unsigned short*)w;
    int ok = 1;
    #pragma unroll
    for (int t = 0; t < 64; ++t) { float v = bf2f(u[t]); ok &= (fabsf(v) < 1.0f) ? 1 : 0; }
    return ok;
}
__device__ __forceinline__ float ldf(const void* p, int idx, int isbf) {
    return isbf ? bf2f(((const unsigned short*)p)[idx]) : ((const float*)p)[idx];
}

__device__ __forceinline__ void load8f(const float* rowp, int kb, int kmax,
                                       int valid, float* x) {
    if (valid && kb + 8 <= kmax) {
        float4 a = *(const float4*)(rowp + kb);
        float4 b = *(const float4*)(rowp + kb + 4);
        x[0]=a.x; x[1]=a.y; x[2]=a.z; x[3]=a.w;
        x[4]=b.x; x[5]=b.y; x[6]=b.z; x[7]=b.w;
    } else {
        #pragma unroll
        for (int j = 0; j < 8; ++j) {
            int k = kb + j;
            x[j] = (valid && k < kmax) ? rowp[k] : 0.f;
        }
    }
}
__device__ __forceinline__ short8 pack8(const float* x) {
    S8 H;
    #pragma unroll
    for (int p = 0; p < 4; ++p) {
        union { float f; unsigned int i; } a, b;
        a.f = x[2*p]; b.f = x[2*p+1];
        H.u[p] = ((a.i + 0x8000u) >> 16) | ((b.i + 0x8000u) & 0xFFFF0000u);
    }
    return H.v;
}
__device__ __forceinline__ short8 load8bf(const unsigned short* rowp, int kb,
                                          int kmax, int valid) {
    S8 R;
    if (valid && kb + 8 <= kmax) {
        ushort4 a = *(const ushort4*)(rowp + kb);
        ushort4 b = *(const ushort4*)(rowp + kb + 4);
        R.s[0]=a.x; R.s[1]=a.y; R.s[2]=a.z; R.s[3]=a.w;
        R.s[4]=b.x; R.s[5]=b.y; R.s[6]=b.z; R.s[7]=b.w;
    } else {
        #pragma unroll
        for (int j = 0; j < 8; ++j) {
            int k = kb + j;
            R.s[j] = (valid && k < kmax) ? rowp[k] : (unsigned short)0;
        }
    }
    return R.v;
}
__device__ __forceinline__ short8 loadB(const void* W, int row, int kb, int isbf,
                                        int valid) {
    if (isbf) return load8bf((const unsigned short*)W + row * 300, kb, 300, valid);
    float t[8];
    load8f((const float*)W + row * 300, kb, 300, valid, t);
    return pack8(t);
}

// ---------------------------------------------------------------------------
// Software grid barrier. All 640 blocks are co-resident (launch_bounds(320,4)
// => VGPR<=128 => 3 blocks/CU => 768-block capacity). Agent-scope ACQ_REL
// chain through the counter gives cross-XCD visibility of prior writes.
// Spin has an escape hatch: a lost block turns into a visible verify failure,
// never a hung container.
// ---------------------------------------------------------------------------
__device__ __forceinline__ void gbar(float* ws, int idx, int nblk) {
    __syncthreads();
    if (threadIdx.x == 0) {
        int* s = (int*)(ws + SYNC_FOFF) + idx * 32;     // 128 B apart
        int a = __hip_atomic_fetch_add(s, 1, __ATOMIC_ACQ_REL,
                                       __HIP_MEMORY_SCOPE_AGENT);
        if (a == nblk - 1) {
            __hip_atomic_store(s + 16, 1, __ATOMIC_RELEASE,
                               __HIP_MEMORY_SCOPE_AGENT);
        } else {
            int t = 0;
            while (__hip_atomic_load(s + 16, __ATOMIC_ACQUIRE,
                                     __HIP_MEMORY_SCOPE_AGENT) == 0) {
                __builtin_amdgcn_s_sleep(2);
                if (++t > 400000) break;                // ~40 ms escape hatch
            }
        }
    }
    __syncthreads();
}

// ---------------------------------------------------------------------------
// Fused DiSA forward: mm1 -> bar -> mm2 -> bar -> attn -> bar -> mm3.
// grid 640 x 320 threads (5 waves).
// ---------------------------------------------------------------------------
__global__ __launch_bounds__(320, 4) void k_fused(
        const void* __restrict__ Xv, const int* __restrict__ mask,
        const void* __restrict__ Wfc, const void* __restrict__ bfc,
        const void* __restrict__ W1,  const void* __restrict__ W2,
        const void* __restrict__ b1v, const void* __restrict__ Wf1,
        const void* __restrict__ Wf2, const void* __restrict__ bfv,
        float* __restrict__ ws, void* __restrict__ outv) {
    __shared__ int s_isbf;
    __shared__ unsigned short vlist[256];
    __shared__ int s_cnt, s_st0, s_st1;

    const int tid = threadIdx.x;
    const int blk = blockIdx.x;
    if (tid == 0) s_isbf = detect_bf16(Wfc);
    __syncthreads();
    const int isbf = s_isbf;
    unsigned short* U = (unsigned short*)(ws + U_BASE);

    // ---- Stage 1: rep = elu(X@Wfc^T + bfc) (blocks 0..319);
    //               pack W1/W2/Wf1/Wf2 -> bf16 [320][320] (blocks 320..639) ----
    if (blk < 320) {
        if (tid < 256) {
            const int w = tid >> 6, l = tid & 63;
            const int mt = blk / 5, nt = blk % 5;
            const int m0 = mt * 16, lm = l & 15, koff = (l >> 4) * 8;
            const int nrow = nt * 64 + w * 16 + lm;          // 0..319
            const int bval = nrow < 300;
            const int ncl = bval ? nrow : 0;
            f32x4 acc = {0.f, 0.f, 0.f, 0.f};
            if (isbf) {
                const unsigned short* Xp = (const unsigned short*)Xv + (m0 + lm) * 300;
                #pragma unroll
                for (int ks = 0; ks < 10; ++ks) {
                    short8 a = load8bf(Xp, ks*32 + koff, 300, 1);
                    short8 b = loadB(Wfc, ncl, ks*32 + koff, 1, bval);
                    acc = __builtin_amdgcn_mfma_f32_16x16x32_bf16(a, b, acc, 0, 0, 0);
                }
            } else {
                const float* Xp = (const float*)Xv + (m0 + lm) * 300;
                #pragma unroll
                for (int ks = 0; ks < 10; ++ks) {
                    float t[8]; load8f(Xp, ks*32 + koff, 300, 1, t);
                    short8 a = pack8(t);
                    short8 b = loadB(Wfc, ncl, ks*32 + koff, 0, bval);
                    acc = __builtin_amdgcn_mfma_f32_16x16x32_bf16(a, b, acc, 0, 0, 0);
                }
            }
            if (bval) {
                float bb = ldf(bfc, nrow, isbf);
                #pragma unroll
                for (int r = 0; r < 4; ++r) {
                    int mg = m0 + (l >> 4) * 4 + r;
                    float v = acc[r] + bb;
                    v = v > 0.f ? v : (__expf(v) - 1.f);
                    ws[OFF_REP + mg * 300 + nrow] = v;
                    U[REPB + mg * 320 + nrow] = f2bf(v);
                }
            } else {
                #pragma unroll
                for (int r = 0; r < 4; ++r) {
                    int mg = m0 + (l >> 4) * 4 + r;
                    U[REPB + mg * 320 + nrow] = 0;
                }
            }
        }
    } else {
        const int pid = (blk - 320) * 320 + tid;   // 0..102399
        const int row = pid / 320, k = pid - row * 320;
        const int inb = (row < 300) & (k < 300);
        const int off = row * 300 + k;
        const void* srcs[4] = {W1, W2, Wf1, Wf2};
        #pragma unroll
        for (int c = 0; c < 4; ++c) {
            float v = inb ? ldf(srcs[c], off, isbf) : 0.f;
            U[WPACK + c * 102400 + pid] = f2bf(v);
        }
    }
    gbar(ws, 0, 640);

    // ---- Stage 2: dep/head = rep @ {W1,W2}^T; dep -> exd = exp(0.4*(dep+b1)).
    //               640 units == grid, one per block. ----
    if (tid < 256) {
        const int w = tid >> 6, l = tid & 63;
        const int mt = blk / 10, nt = blk % 10;
        const int m0 = mt * 16, lm = l & 15, koff = (l >> 4) * 8;
        const int ng = nt * 64 + w * 16 + lm;            // 0..639
        const int wsel = ng < 320;
        const int wrow = wsel ? ng : ng - 320;           // packed rows >=300 are zero
        const unsigned short* Uc = U;
        const unsigned short* ap = Uc + REPB + (m0 + lm) * 320 + koff;
        const unsigned short* bp = Uc + (wsel ? WP1 : WP2) + wrow * 320 + koff;
        f32x4 acc = {0.f, 0.f, 0.f, 0.f};
        #pragma unroll
        for (int ks = 0; ks < 10; ++ks) {
            short8 a = *(const short8*)(ap + ks * 32);
            short8 b = *(const short8*)(bp + ks * 32);
            acc = __builtin_amdgcn_mfma_f32_16x16x32_bf16(a, b, acc, 0, 0, 0);
        }
        if (ng < 300) {
            float bb = ldf(b1v, ng, isbf);
            #pragma unroll
            for (int r = 0; r < 4; ++r) {
                int mg = m0 + (l >> 4) * 4 + r;
                ws[OFF_DEP + mg * 300 + ng] = __expf(0.4f * (acc[r] + bb));
            }
        } else if (ng >= 320 && ng < 620) {
            #pragma unroll
            for (int r = 0; r < 4; ++r) {
                int mg = m0 + (l >> 4) * 4 + r;
                ws[OFF_HEAD + mg * 300 + (ng - 320)] = acc[r];
            }
        }
    }
    gbar(ws, 1, 640);

    // ---- Stage 3: attention, 512 i-pair units; SKIP rows with rep_mask[i]=0
    //               (their outputs are zeroed by the final mask; mm3 epilogue
    //                is guarded so their poisoned attn rows are never read). ----
    if (blk < 512) {
        const int b = blk >> 7;
        const int tile = blk & 127;
        const int uu = tile >> 1;
        const int i0 = (tile & 1) ? (254 - 2 * uu) : (2 * uu);
        const int base = b * 256;
        const int mv0 = mask[base + i0] != 0;
        const int mv1 = mask[base + i0 + 1] != 0;
        if ((mv0 | mv1) && tid < 64) {
            int basec = 0, st0 = 0, st1 = 0;
            #pragma unroll
            for (int c = 0; c < 4; ++c) {
                const int j = c * 64 + tid;
                const int mv = mask[base + j] != 0;
                unsigned long long bal = __ballot(mv);
                int pos = basec + __popcll(bal & ((1ull << tid) - 1ull));
                if (mv) vlist[pos] = (unsigned short)j;
                if (tid == 0) {
                    int lim0 = i0 - c * 64;
                    if (lim0 >= 0)
                        st0 += __popcll(bal & (lim0 >= 63 ? ~0ull : ((2ull << lim0) - 1ull)));
                    int lim1 = i0 + 1 - c * 64;
                    if (lim1 >= 0)
                        st1 += __popcll(bal & (lim1 >= 63 ? ~0ull : ((2ull << lim1) - 1ull)));
                }
                basec += __popcll(bal);
            }
            if (tid == 0) { s_cnt = basec; s_st0 = st0; s_st1 = st1; }
        }
        __syncthreads();
        const int d = tid;
        if (d >= 300) {
            U[ATB + (base + i0) * 320 + d] = 0;
            U[ATB + (base + i0 + 1) * 320 + d] = 0;
        } else if (mv0 & mv1) {
            const int cnt = s_cnt, st0 = s_st0, st1 = s_st1;
            const float* headp = ws + OFF_HEAD;
            const float hv0 = headp[(base + i0) * Dx + d];
            const float hv1 = headp[(base + i0 + 1) * Dx + d];
            const float pw0 = __expf(0.4f * hv0);
            const float pw1 = __expf(0.4f * hv1);
            const float* ep = ws + OFF_DEP + base * Dx + d;
            const float* rp = ws + OFF_REP + base * Dx + d;
            float s0 = 0.f, r0 = 0.f, s1 = 0.f, r1 = 0.f;
            if (st1 > st0) {
                const int j = vlist[st0];
                float ex = ep[j * Dx];
                float rv = rp[j * Dx];
                float u0 = fmaf(ex, pw0, 1.0f);
                float e0 = __expf(-10.0f * __builtin_amdgcn_rcpf(u0));
                s0 += e0; r0 = fmaf(e0, rv, r0);
            }
            #pragma unroll 4
            for (int t = st1; t < cnt; ++t) {
                const int j = vlist[t];
                float ex = ep[j * Dx];
                float rv = rp[j * Dx];
                float u0 = fmaf(ex, pw0, 1.0f);
                float u1 = fmaf(ex, pw1, 1.0f);
                float e0 = __expf(-10.0f * __builtin_amdgcn_rcpf(u0));
                float e1 = __expf(-10.0f * __builtin_amdgcn_rcpf(u1));
                s0 += e0; r0 = fmaf(e0, rv, r0);
                s1 += e1; r1 = fmaf(e1, rv, r1);
            }
            const float den0 = s0 + (s0 == 0.f ? 1.f : 0.f) + 1e-20f;
            const float den1 = s1 + (s1 == 0.f ? 1.f : 0.f) + 1e-20f;
            const float a0 = r0 / den0, a1 = r1 / den1;
            ws[OFF_ATTN + (base + i0) * Dx + d]     = a0;
            ws[OFF_ATTN + (base + i0 + 1) * Dx + d] = a1;
            U[ATB + (base + i0) * 320 + d]     = f2bf(a0);
            U[ATB + (base + i0 + 1) * 320 + d] = f2bf(a1);
        } else if (mv0 | mv1) {
            const int cnt = s_cnt;
            const int ia  = mv0 ? i0 : (i0 + 1);
            const int sta = mv0 ? s_st0 : s_st1;
            const float hv = (ws + OFF_HEAD)[(base + ia) * Dx + d];
            const float pw = __expf(0.4f * hv);
            const float* ep = ws + OFF_DEP + base * Dx + d;
            const float* rp = ws + OFF_REP + base * Dx + d;
            float s = 0.f, r = 0.f;
            #pragma unroll 4
            for (int t = sta; t < cnt; ++t) {
                const int j = vlist[t];
                float ex = ep[j * Dx];
                float rv = rp[j * Dx];
                float u0 = fmaf(ex, pw, 1.0f);
                float e  = __expf(-10.0f * __builtin_amdgcn_rcpf(u0));
                s += e; r = fmaf(e, rv, r);
            }
            const float den = s + (s == 0.f ? 1.f : 0.f) + 1e-20f;
            const float a = r / den;
            ws[OFF_ATTN + (base + ia) * Dx + d] = a;
            U[ATB + (base + ia) * 320 + d] = f2bf(a);
        }
    }
    gbar(ws, 2, 640);

    // ---- Stage 4: gate = sigmoid(rep@Wf1^T + attn@Wf2^T + bf); blend; mask. ----
    if (blk < 320 && tid < 256) {
        const int w = tid >> 6, l = tid & 63;
        const int mt = blk / 5, nt = blk % 5;
        const int m0 = mt * 16, lm = l & 15, koff = (l >> 4) * 8;
        const int nrow = nt * 64 + w * 16 + lm;          // 0..319 (rows >=300 zero)
        const unsigned short* Uc = U;
        const unsigned short* a1p = Uc + REPB + (m0 + lm) * 320 + koff;
        const unsigned short* a2p = Uc + ATB  + (m0 + lm) * 320 + koff;
        const unsigned short* b1p = Uc + WPF1 + nrow * 320 + koff;
        const unsigned short* b2p = Uc + WPF2 + nrow * 320 + koff;
        f32x4 acc = {0.f, 0.f, 0.f, 0.f};
        #pragma unroll
        for (int ks = 0; ks < 10; ++ks) {
            short8 a = *(const short8*)(a1p + ks * 32);
            short8 b = *(const short8*)(b1p + ks * 32);
            acc = __builtin_amdgcn_mfma_f32_16x16x32_bf16(a, b, acc, 0, 0, 0);
        }
        #pragma unroll
        for (int ks = 0; ks < 10; ++ks) {
            short8 a = *(const short8*)(a2p + ks * 32);
            short8 b = *(const short8*)(b2p + ks * 32);
            acc = __builtin_amdgcn_mfma_f32_16x16x32_bf16(a, b, acc, 0, 0, 0);
        }
        if (nrow < 300) {
            float bb = ldf(bfv, nrow, isbf);
            #pragma unroll
            for (int r = 0; r < 4; ++r) {
                int mg = m0 + (l >> 4) * 4 + r;
                float res = 0.f;
                if (mask[mg]) {
                    float gp = acc[r] + bb;
                    float gate = 1.0f / (1.0f + __expf(-gp));
                    float rv = ws[OFF_REP  + mg * 300 + nrow];
                    float av = ws[OFF_ATTN + mg * 300 + nrow];
                    res = gate * rv + (1.0f - gate) * av;
                }
                if (isbf) ((__hip_bfloat16*)outv)[mg * 300 + nrow] = __float2bfloat16(res);
                else      ((float*)outv)[mg * 300 + nrow] = res;
            }
        }
    }
}

extern "C" void kernel_launch(void* const* d_in, const int* in_sizes, int n_in,
                              void* d_out, int out_size, void* d_ws, size_t ws_size,
                              hipStream_t stream) {
    const void* X   = d_in[0];
    const int*  msk = (const int*)d_in[1];
    const void* Wfc = d_in[2];
    const void* bfc = d_in[3];
    const void* W1  = d_in[4];
    const void* W2  = d_in[5];
    const void* b1  = d_in[6];
    const void* Wf1 = d_in[7];
    const void* Wf2 = d_in[8];
    const void* bfv = d_in[9];
    float* ws = (float*)d_ws;

    // zero the software-barrier counters (capturable memset node)
    hipMemsetAsync((char*)d_ws + (size_t)SYNC_FOFF * sizeof(float), 0, 512, stream);

    hipLaunchKernelGGL(k_fused, dim3(640), dim3(320), 0, stream,
                       X, msk, Wfc, bfc, W1, W2, b1, Wf1, Wf2, bfv, ws, d_out);
}

// Round 3
// 189.558 us; speedup vs baseline: 2.5135x; 2.5135x over previous
//
#include <hip/hip_runtime.h>
#include <hip/hip_bf16.h>

#define Dx 300

// float-offsets into ws
#define OFF_REP    0
#define OFF_DEP    307200      // holds exd = exp(0.4*(dep+b1))
#define OFF_HEAD   614400
#define OFF_ATTN   921600
// ushort arrays at U = (ushort*)(ws + 1228800): zero-padded
#define U_BASE     1228800
#define REPB       0           // [1024][320]
#define ATB        327680      // [1024][320]
#define WPACK      655360      // 4 x [320][320]: W1, W2, Wf1, Wf2 (contiguous)
#define WP1        655360
#define WP2        757760
#define WPF1       860160
#define WPF2       962560
// software grid-barrier state (zeroed by hipMemsetAsync before launch)
#define SYNC_FOFF  2000000     // float offset, 8 MB into ws — clear of all data

typedef __attribute__((ext_vector_type(8))) short short8;
typedef __attribute__((ext_vector_type(4))) float f32x4;

union S8 { unsigned int u[4]; unsigned short s[8]; short8 v; };

__device__ __forceinline__ float bf2f(unsigned short u) {
    union { unsigned int i; float f; } v; v.i = ((unsigned int)u) << 16; return v.f;
}
__device__ __forceinline__ unsigned short f2bf(float x) {   // round-half-up
    union { float f; unsigned int i; } u; u.f = x;
    return (unsigned short)((u.i + 0x8000u) >> 16);
}
__device__ __forceinline__ int detect_bf16(const void* w) {
    const unsigned short* u = (const unsigned short*)w;
    int ok = 1;
    #pragma unroll
    for (int t = 0; t < 64; ++t) { float v = bf2f(u[t]); ok &= (fabsf(v) < 1.0f) ? 1 : 0; }
    return ok;
}
__device__ __forceinline__ float ldf(const void* p, int idx, int isbf) {
    return isbf ? bf2f(((const unsigned short*)p)[idx]) : ((const float*)p)[idx];
}

__device__ __forceinline__ void load8f(const float* rowp, int kb, int kmax,
                                       int valid, float* x) {
    if (valid && kb + 8 <= kmax) {
        float4 a = *(const float4*)(rowp + kb);
        float4 b = *(const float4*)(rowp + kb + 4);
        x[0]=a.x; x[1]=a.y; x[2]=a.z; x[3]=a.w;
        x[4]=b.x; x[5]=b.y; x[6]=b.z; x[7]=b.w;
    } else {
        #pragma unroll
        for (int j = 0; j < 8; ++j) {
            int k = kb + j;
            x[j] = (valid && k < kmax) ? rowp[k] : 0.f;
        }
    }
}
__device__ __forceinline__ short8 pack8(const float* x) {
    S8 H;
    #pragma unroll
    for (int p = 0; p < 4; ++p) {
        union { float f; unsigned int i; } a, b;
        a.f = x[2*p]; b.f = x[2*p+1];
        H.u[p] = ((a.i + 0x8000u) >> 16) | ((b.i + 0x8000u) & 0xFFFF0000u);
    }
    return H.v;
}
__device__ __forceinline__ short8 load8bf(const unsigned short* rowp, int kb,
                                          int kmax, int valid) {
    S8 R;
    if (valid && kb + 8 <= kmax) {
        ushort4 a = *(const ushort4*)(rowp + kb);
        ushort4 b = *(const ushort4*)(rowp + kb + 4);
        R.s[0]=a.x; R.s[1]=a.y; R.s[2]=a.z; R.s[3]=a.w;
        R.s[4]=b.x; R.s[5]=b.y; R.s[6]=b.z; R.s[7]=b.w;
    } else {
        #pragma unroll
        for (int j = 0; j < 8; ++j) {
            int k = kb + j;
            R.s[j] = (valid && k < kmax) ? rowp[k] : (unsigned short)0;
        }
    }
    return R.v;
}
__device__ __forceinline__ short8 loadB(const void* W, int row, int kb, int isbf,
                                        int valid) {
    if (isbf) return load8bf((const unsigned short*)W + row * 300, kb, 300, valid);
    float t[8];
    load8f((const float*)W + row * 300, kb, 300, valid, t);
    return pack8(t);
}

// ---------------------------------------------------------------------------
// Software grid barrier, v2 — minimal cache maintenance.
// Arrival: fetch_add(RELEASE) => one buffer_wbl2 (producer data leaves L2),
// no invalidate. Waiters: RELAXED agent loads (per-address sc1 bypass, NO
// whole-L2 invalidate) with a periodic ACQUIRE every 64 polls as a progress
// hedge; one final ACQUIRE load (single buffer_inv) before proceeding.
// Round-2's ACQ_REL-per-poll version invalidated L2 every spin iteration —
// that was the 399 us.
// ---------------------------------------------------------------------------
__device__ __forceinline__ void gbar(float* ws, int idx, int nblk) {
    __syncthreads();
    if (threadIdx.x == 0) {
        int* cnt  = (int*)(ws + SYNC_FOFF) + idx * 64;   // 256 B apart
        int* flag = cnt + 32;                            // 128 B from cnt
        int old = __hip_atomic_fetch_add(cnt, 1, __ATOMIC_RELEASE,
                                         __HIP_MEMORY_SCOPE_AGENT);
        if (old == nblk - 1) {
            (void)__hip_atomic_load(cnt, __ATOMIC_ACQUIRE,
                                    __HIP_MEMORY_SCOPE_AGENT);
            __hip_atomic_store(flag, 1, __ATOMIC_RELEASE,
                               __HIP_MEMORY_SCOPE_AGENT);
        } else {
            int t = 0;
            for (;;) {
                int f = (t & 63)
                    ? __hip_atomic_load(flag, __ATOMIC_RELAXED,
                                        __HIP_MEMORY_SCOPE_AGENT)
                    : __hip_atomic_load(flag, __ATOMIC_ACQUIRE,
                                        __HIP_MEMORY_SCOPE_AGENT);
                if (f) break;
                __builtin_amdgcn_s_sleep(2);
                if (++t > 150000) break;                 // ~12 ms escape hatch
            }
            (void)__hip_atomic_load(flag, __ATOMIC_ACQUIRE,
                                    __HIP_MEMORY_SCOPE_AGENT);
        }
    }
    __syncthreads();
}

// ---------------------------------------------------------------------------
// Fused DiSA forward: mm1 -> bar -> mm2 -> bar -> attn -> bar -> mm3.
// grid 640 x 320 threads (5 waves).
// ---------------------------------------------------------------------------
__global__ __launch_bounds__(320, 4) void k_fused(
        const void* __restrict__ Xv, const int* __restrict__ mask,
        const void* __restrict__ Wfc, const void* __restrict__ bfc,
        const void* __restrict__ W1,  const void* __restrict__ W2,
        const void* __restrict__ b1v, const void* __restrict__ Wf1,
        const void* __restrict__ Wf2, const void* __restrict__ bfv,
        float* __restrict__ ws, void* __restrict__ outv) {
    __shared__ int s_isbf;
    __shared__ unsigned short vlist[256];
    __shared__ int s_cnt, s_st0, s_st1;

    const int tid = threadIdx.x;
    const int blk = blockIdx.x;
    if (tid == 0) s_isbf = detect_bf16(Wfc);
    __syncthreads();
    const int isbf = s_isbf;
    unsigned short* U = (unsigned short*)(ws + U_BASE);

    // ---- Stage 1: rep = elu(X@Wfc^T + bfc) (blocks 0..319);
    //               pack W1/W2/Wf1/Wf2 -> bf16 [320][320] (blocks 320..639) ----
    if (blk < 320) {
        if (tid < 256) {
            const int w = tid >> 6, l = tid & 63;
            const int mt = blk / 5, nt = blk % 5;
            const int m0 = mt * 16, lm = l & 15, koff = (l >> 4) * 8;
            const int nrow = nt * 64 + w * 16 + lm;          // 0..319
            const int bval = nrow < 300;
            const int ncl = bval ? nrow : 0;
            f32x4 acc = {0.f, 0.f, 0.f, 0.f};
            if (isbf) {
                const unsigned short* Xp = (const unsigned short*)Xv + (m0 + lm) * 300;
                #pragma unroll
                for (int ks = 0; ks < 10; ++ks) {
                    short8 a = load8bf(Xp, ks*32 + koff, 300, 1);
                    short8 b = loadB(Wfc, ncl, ks*32 + koff, 1, bval);
                    acc = __builtin_amdgcn_mfma_f32_16x16x32_bf16(a, b, acc, 0, 0, 0);
                }
            } else {
                const float* Xp = (const float*)Xv + (m0 + lm) * 300;
                #pragma unroll
                for (int ks = 0; ks < 10; ++ks) {
                    float t[8]; load8f(Xp, ks*32 + koff, 300, 1, t);
                    short8 a = pack8(t);
                    short8 b = loadB(Wfc, ncl, ks*32 + koff, 0, bval);
                    acc = __builtin_amdgcn_mfma_f32_16x16x32_bf16(a, b, acc, 0, 0, 0);
                }
            }
            if (bval) {
                float bb = ldf(bfc, nrow, isbf);
                #pragma unroll
                for (int r = 0; r < 4; ++r) {
                    int mg = m0 + (l >> 4) * 4 + r;
                    float v = acc[r] + bb;
                    v = v > 0.f ? v : (__expf(v) - 1.f);
                    ws[OFF_REP + mg * 300 + nrow] = v;
                    U[REPB + mg * 320 + nrow] = f2bf(v);
                }
            } else {
                #pragma unroll
                for (int r = 0; r < 4; ++r) {
                    int mg = m0 + (l >> 4) * 4 + r;
                    U[REPB + mg * 320 + nrow] = 0;
                }
            }
        }
    } else {
        const int pid = (blk - 320) * 320 + tid;   // 0..102399
        const int row = pid / 320, k = pid - row * 320;
        const int inb = (row < 300) & (k < 300);
        const int off = row * 300 + k;
        const void* srcs[4] = {W1, W2, Wf1, Wf2};
        #pragma unroll
        for (int c = 0; c < 4; ++c) {
            float v = inb ? ldf(srcs[c], off, isbf) : 0.f;
            U[WPACK + c * 102400 + pid] = f2bf(v);
        }
    }
    gbar(ws, 0, 640);

    // ---- Stage 2: dep/head = rep @ {W1,W2}^T; dep -> exd = exp(0.4*(dep+b1)).
    //               640 units == grid, one per block. ----
    if (tid < 256) {
        const int w = tid >> 6, l = tid & 63;
        const int mt = blk / 10, nt = blk % 10;
        const int m0 = mt * 16, lm = l & 15, koff = (l >> 4) * 8;
        const int ng = nt * 64 + w * 16 + lm;            // 0..639
        const int wsel = ng < 320;
        const int wrow = wsel ? ng : ng - 320;           // packed rows >=300 are zero
        const unsigned short* Uc = U;
        const unsigned short* ap = Uc + REPB + (m0 + lm) * 320 + koff;
        const unsigned short* bp = Uc + (wsel ? WP1 : WP2) + wrow * 320 + koff;
        f32x4 acc = {0.f, 0.f, 0.f, 0.f};
        #pragma unroll
        for (int ks = 0; ks < 10; ++ks) {
            short8 a = *(const short8*)(ap + ks * 32);
            short8 b = *(const short8*)(bp + ks * 32);
            acc = __builtin_amdgcn_mfma_f32_16x16x32_bf16(a, b, acc, 0, 0, 0);
        }
        if (ng < 300) {
            float bb = ldf(b1v, ng, isbf);
            #pragma unroll
            for (int r = 0; r < 4; ++r) {
                int mg = m0 + (l >> 4) * 4 + r;
                ws[OFF_DEP + mg * 300 + ng] = __expf(0.4f * (acc[r] + bb));
            }
        } else if (ng >= 320 && ng < 620) {
            #pragma unroll
            for (int r = 0; r < 4; ++r) {
                int mg = m0 + (l >> 4) * 4 + r;
                ws[OFF_HEAD + mg * 300 + (ng - 320)] = acc[r];
            }
        }
    }
    gbar(ws, 1, 640);

    // ---- Stage 3: attention, 512 i-pair units; SKIP rows with rep_mask[i]=0
    //               (their outputs are zeroed by the final mask; mm3 epilogue
    //                is guarded so their poisoned attn rows are never read). ----
    if (blk < 512) {
        const int b = blk >> 7;
        const int tile = blk & 127;
        const int uu = tile >> 1;
        const int i0 = (tile & 1) ? (254 - 2 * uu) : (2 * uu);
        const int base = b * 256;
        const int mv0 = mask[base + i0] != 0;
        const int mv1 = mask[base + i0 + 1] != 0;
        if ((mv0 | mv1) && tid < 64) {
            int basec = 0, st0 = 0, st1 = 0;
            #pragma unroll
            for (int c = 0; c < 4; ++c) {
                const int j = c * 64 + tid;
                const int mv = mask[base + j] != 0;
                unsigned long long bal = __ballot(mv);
                int pos = basec + __popcll(bal & ((1ull << tid) - 1ull));
                if (mv) vlist[pos] = (unsigned short)j;
                if (tid == 0) {
                    int lim0 = i0 - c * 64;
                    if (lim0 >= 0)
                        st0 += __popcll(bal & (lim0 >= 63 ? ~0ull : ((2ull << lim0) - 1ull)));
                    int lim1 = i0 + 1 - c * 64;
                    if (lim1 >= 0)
                        st1 += __popcll(bal & (lim1 >= 63 ? ~0ull : ((2ull << lim1) - 1ull)));
                }
                basec += __popcll(bal);
            }
            if (tid == 0) { s_cnt = basec; s_st0 = st0; s_st1 = st1; }
        }
        __syncthreads();
        const int d = tid;
        if (d >= 300) {
            U[ATB + (base + i0) * 320 + d] = 0;
            U[ATB + (base + i0 + 1) * 320 + d] = 0;
        } else if (mv0 & mv1) {
            const int cnt = s_cnt, st0 = s_st0, st1 = s_st1;
            const float* headp = ws + OFF_HEAD;
            const float hv0 = headp[(base + i0) * Dx + d];
            const float hv1 = headp[(base + i0 + 1) * Dx + d];
            const float pw0 = __expf(0.4f * hv0);
            const float pw1 = __expf(0.4f * hv1);
            const float* ep = ws + OFF_DEP + base * Dx + d;
            const float* rp = ws + OFF_REP + base * Dx + d;
            float s0 = 0.f, r0 = 0.f, s1 = 0.f, r1 = 0.f;
            if (st1 > st0) {
                const int j = vlist[st0];
                float ex = ep[j * Dx];
                float rv = rp[j * Dx];
                float u0 = fmaf(ex, pw0, 1.0f);
                float e0 = __expf(-10.0f * __builtin_amdgcn_rcpf(u0));
                s0 += e0; r0 = fmaf(e0, rv, r0);
            }
            #pragma unroll 4
            for (int t = st1; t < cnt; ++t) {
                const int j = vlist[t];
                float ex = ep[j * Dx];
                float rv = rp[j * Dx];
                float u0 = fmaf(ex, pw0, 1.0f);
                float u1 = fmaf(ex, pw1, 1.0f);
                float e0 = __expf(-10.0f * __builtin_amdgcn_rcpf(u0));
                float e1 = __expf(-10.0f * __builtin_amdgcn_rcpf(u1));
                s0 += e0; r0 = fmaf(e0, rv, r0);
                s1 += e1; r1 = fmaf(e1, rv, r1);
            }
            const float den0 = s0 + (s0 == 0.f ? 1.f : 0.f) + 1e-20f;
            const float den1 = s1 + (s1 == 0.f ? 1.f : 0.f) + 1e-20f;
            const float a0 = r0 / den0, a1 = r1 / den1;
            ws[OFF_ATTN + (base + i0) * Dx + d]     = a0;
            ws[OFF_ATTN + (base + i0 + 1) * Dx + d] = a1;
            U[ATB + (base + i0) * 320 + d]     = f2bf(a0);
            U[ATB + (base + i0 + 1) * 320 + d] = f2bf(a1);
        } else if (mv0 | mv1) {
            const int cnt = s_cnt;
            const int ia  = mv0 ? i0 : (i0 + 1);
            const int sta = mv0 ? s_st0 : s_st1;
            const float hv = (ws + OFF_HEAD)[(base + ia) * Dx + d];
            const float pw = __expf(0.4f * hv);
            const float* ep = ws + OFF_DEP + base * Dx + d;
            const float* rp = ws + OFF_REP + base * Dx + d;
            float s = 0.f, r = 0.f;
            #pragma unroll 4
            for (int t = sta; t < cnt; ++t) {
                const int j = vlist[t];
                float ex = ep[j * Dx];
                float rv = rp[j * Dx];
                float u0 = fmaf(ex, pw, 1.0f);
                float e  = __expf(-10.0f * __builtin_amdgcn_rcpf(u0));
                s += e; r = fmaf(e, rv, r);
            }
            const float den = s + (s == 0.f ? 1.f : 0.f) + 1e-20f;
            const float a = r / den;
            ws[OFF_ATTN + (base + ia) * Dx + d] = a;
            U[ATB + (base + ia) * 320 + d] = f2bf(a);
        }
    }
    gbar(ws, 2, 640);

    // ---- Stage 4: gate = sigmoid(rep@Wf1^T + attn@Wf2^T + bf); blend; mask. ----
    if (blk < 320 && tid < 256) {
        const int w = tid >> 6, l = tid & 63;
        const int mt = blk / 5, nt = blk % 5;
        const int m0 = mt * 16, lm = l & 15, koff = (l >> 4) * 8;
        const int nrow = nt * 64 + w * 16 + lm;          // 0..319 (rows >=300 zero)
        const unsigned short* Uc = U;
        const unsigned short* a1p = Uc + REPB + (m0 + lm) * 320 + koff;
        const unsigned short* a2p = Uc + ATB  + (m0 + lm) * 320 + koff;
        const unsigned short* b1p = Uc + WPF1 + nrow * 320 + koff;
        const unsigned short* b2p = Uc + WPF2 + nrow * 320 + koff;
        f32x4 acc = {0.f, 0.f, 0.f, 0.f};
        #pragma unroll
        for (int ks = 0; ks < 10; ++ks) {
            short8 a = *(const short8*)(a1p + ks * 32);
            short8 b = *(const short8*)(b1p + ks * 32);
            acc = __builtin_amdgcn_mfma_f32_16x16x32_bf16(a, b, acc, 0, 0, 0);
        }
        #pragma unroll
        for (int ks = 0; ks < 10; ++ks) {
            short8 a = *(const short8*)(a2p + ks * 32);
            short8 b = *(const short8*)(b2p + ks * 32);
            acc = __builtin_amdgcn_mfma_f32_16x16x32_bf16(a, b, acc, 0, 0, 0);
        }
        if (nrow < 300) {
            float bb = ldf(bfv, nrow, isbf);
            #pragma unroll
            for (int r = 0; r < 4; ++r) {
                int mg = m0 + (l >> 4) * 4 + r;
                float res = 0.f;
                if (mask[mg]) {
                    float gp = acc[r] + bb;
                    float gate = 1.0f / (1.0f + __expf(-gp));
                    float rv = ws[OFF_REP  + mg * 300 + nrow];
                    float av = ws[OFF_ATTN + mg * 300 + nrow];
                    res = gate * rv + (1.0f - gate) * av;
                }
                if (isbf) ((__hip_bfloat16*)outv)[mg * 300 + nrow] = __float2bfloat16(res);
                else      ((float*)outv)[mg * 300 + nrow] = res;
            }
        }
    }
}

extern "C" void kernel_launch(void* const* d_in, const int* in_sizes, int n_in,
                              void* d_out, int out_size, void* d_ws, size_t ws_size,
                              hipStream_t stream) {
    const void* X   = d_in[0];
    const int*  msk = (const int*)d_in[1];
    const void* Wfc = d_in[2];
    const void* bfc = d_in[3];
    const void* W1  = d_in[4];
    const void* W2  = d_in[5];
    const void* b1  = d_in[6];
    const void* Wf1 = d_in[7];
    const void* Wf2 = d_in[8];
    const void* bfv = d_in[9];
    float* ws = (float*)d_ws;

    // zero the software-barrier counters (capturable memset node)
    hipMemsetAsync((char*)d_ws + (size_t)SYNC_FOFF * sizeof(float), 0, 1024, stream);

    hipLaunchKernelGGL(k_fused, dim3(640), dim3(320), 0, stream,
                       X, msk, Wfc, bfc, W1, W2, b1, Wf1, Wf2, bfv, ws, d_out);
}

// Round 4
// 164.240 us; speedup vs baseline: 2.9010x; 1.1542x over previous
//
#include <hip/hip_runtime.h>
#include <hip/hip_bf16.h>

#define Dx 300

// float-offsets into ws
#define OFF_REP    0
#define OFF_DEP    307200      // holds exd = exp(0.4*(dep+b1))
#define OFF_HEAD   614400
#define OFF_ATTN   921600
// ushort arrays at U = (ushort*)(ws + 1228800): zero-padded
#define U_BASE     1228800
#define REPB       0           // [1024][320]
#define ATB        327680      // [1024][320]
#define WPACK      655360      // 4 x [320][320]: W1, W2, Wf1, Wf2 (contiguous)
#define WP1        655360
#define WP2        757760
#define WPF1       860160
#define WPF2       962560
// software grid-barrier state (zeroed by hipMemsetAsync before launch)
#define SYNC_FOFF  2000000     // float offset, 8 MB into ws — clear of all data

#define NBLK 320
#define NGRP 10                // 32 blocks per group

typedef __attribute__((ext_vector_type(8))) short short8;
typedef __attribute__((ext_vector_type(4))) float f32x4;

union S8 { unsigned int u[4]; unsigned short s[8]; short8 v; };

__device__ __forceinline__ float bf2f(unsigned short u) {
    union { unsigned int i; float f; } v; v.i = ((unsigned int)u) << 16; return v.f;
}
__device__ __forceinline__ unsigned short f2bf(float x) {   // round-half-up
    union { float f; unsigned int i; } u; u.f = x;
    return (unsigned short)((u.i + 0x8000u) >> 16);
}
__device__ __forceinline__ int detect_bf16(const void* w) {
    const unsigned short* u = (const unsigned short*)w;
    int ok = 1;
    #pragma unroll
    for (int t = 0; t < 64; ++t) { float v = bf2f(u[t]); ok &= (fabsf(v) < 1.0f) ? 1 : 0; }
    return ok;
}
__device__ __forceinline__ float ldf(const void* p, int idx, int isbf) {
    return isbf ? bf2f(((const unsigned short*)p)[idx]) : ((const float*)p)[idx];
}

__device__ __forceinline__ void load8f(const float* rowp, int kb, int kmax,
                                       int valid, float* x) {
    if (valid && kb + 8 <= kmax) {
        float4 a = *(const float4*)(rowp + kb);
        float4 b = *(const float4*)(rowp + kb + 4);
        x[0]=a.x; x[1]=a.y; x[2]=a.z; x[3]=a.w;
        x[4]=b.x; x[5]=b.y; x[6]=b.z; x[7]=b.w;
    } else {
        #pragma unroll
        for (int j = 0; j < 8; ++j) {
            int k = kb + j;
            x[j] = (valid && k < kmax) ? rowp[k] : 0.f;
        }
    }
}
__device__ __forceinline__ short8 pack8(const float* x) {
    S8 H;
    #pragma unroll
    for (int p = 0; p < 4; ++p) {
        union { float f; unsigned int i; } a, b;
        a.f = x[2*p]; b.f = x[2*p+1];
        H.u[p] = ((a.i + 0x8000u) >> 16) | ((b.i + 0x8000u) & 0xFFFF0000u);
    }
    return H.v;
}
__device__ __forceinline__ short8 load8bf(const unsigned short* rowp, int kb,
                                          int kmax, int valid) {
    S8 R;
    if (valid && kb + 8 <= kmax) {
        ushort4 a = *(const ushort4*)(rowp + kb);
        ushort4 b = *(const ushort4*)(rowp + kb + 4);
        R.s[0]=a.x; R.s[1]=a.y; R.s[2]=a.z; R.s[3]=a.w;
        R.s[4]=b.x; R.s[5]=b.y; R.s[6]=b.z; R.s[7]=b.w;
    } else {
        #pragma unroll
        for (int j = 0; j < 8; ++j) {
            int k = kb + j;
            R.s[j] = (valid && k < kmax) ? rowp[k] : (unsigned short)0;
        }
    }
    return R.v;
}
__device__ __forceinline__ short8 loadB(const void* W, int row, int kb, int isbf,
                                        int valid) {
    if (isbf) return load8bf((const unsigned short*)W + row * 300, kb, 300, valid);
    float t[8];
    load8f((const float*)W + row * 300, kb, 300, valid, t);
    return pack8(t);
}

// ---------------------------------------------------------------------------
// Tree grid barrier, v3. 10 groups x 32 blocks -> 10-way root.
//   - arrival RMWs spread over 10 lines (max 32-way contention) + 1 root line
//   - spinners poll group-local flag lines (<=31 readers each) with RELAXED
//     agent loads (no cache maintenance); hedge ACQUIRE every 64th poll only
//   - hb chain: member REL(gcnt) -> leader ACQ(gcnt), REL(rcnt) -> root
//     ACQ(rcnt), REL(rflag) -> leader ACQ(rflag), REL(gflag) -> member
//     ACQ(gflag).  Cross-XCD safe by transitivity.
// Round-3's single-line barrier serialized 640 RMWs + 639 pollers on one
// cache line — that was the ~40 us/barrier.
// ---------------------------------------------------------------------------
#define AG __HIP_MEMORY_SCOPE_AGENT
__device__ __forceinline__ void spin_flag(int* flag) {
    int t = 0;
    for (;;) {
        int f = ((t & 63) == 63)
            ? __hip_atomic_load(flag, __ATOMIC_ACQUIRE, AG)
            : __hip_atomic_load(flag, __ATOMIC_RELAXED, AG);
        if (f) break;
        __builtin_amdgcn_s_sleep(4);
        if (++t > 100000) break;                 // ~30 ms escape hatch
    }
    (void)__hip_atomic_load(flag, __ATOMIC_ACQUIRE, AG);
}

__device__ __forceinline__ void gbar(float* ws, int idx, int blk) {
    __syncthreads();
    if (threadIdx.x == 0) {
        int* base = (int*)(ws + SYNC_FOFF) + idx * 2048;   // 8 KB per barrier
        const int grp = blk >> 5;                          // 0..9
        int* rcnt  = base;                                 // slot 0
        int* rflag = base + 64;                            // slot 1
        int* gcnt  = base + (2 + grp) * 64;                // slots 2..11
        int* gflag = base + (18 + grp) * 64;               // slots 18..27
        int old = __hip_atomic_fetch_add(gcnt, 1, __ATOMIC_RELEASE, AG);
        if (old == 31) {                                   // group leader
            (void)__hip_atomic_load(gcnt, __ATOMIC_ACQUIRE, AG);
            int rold = __hip_atomic_fetch_add(rcnt, 1, __ATOMIC_RELEASE, AG);
            if (rold == NGRP - 1) {
                (void)__hip_atomic_load(rcnt, __ATOMIC_ACQUIRE, AG);
                __hip_atomic_store(rflag, 1, __ATOMIC_RELEASE, AG);
            } else {
                spin_flag(rflag);
            }
            __hip_atomic_store(gflag, 1, __ATOMIC_RELEASE, AG);
        } else {
            spin_flag(gflag);
        }
    }
    __syncthreads();
}

// ---------------------------------------------------------------------------
// Fused DiSA forward: mm1+pack -> bar -> mm2 -> bar -> attn -> bar -> mm3.
// grid 320 x 320 threads (5 waves).
// ---------------------------------------------------------------------------
__global__ __launch_bounds__(320, 4) void k_fused(
        const void* __restrict__ Xv, const int* __restrict__ mask,
        const void* __restrict__ Wfc, const void* __restrict__ bfc,
        const void* __restrict__ W1,  const void* __restrict__ W2,
        const void* __restrict__ b1v, const void* __restrict__ Wf1,
        const void* __restrict__ Wf2, const void* __restrict__ bfv,
        float* __restrict__ ws, void* __restrict__ outv) {
    __shared__ int s_isbf;
    __shared__ unsigned short vlist[256];
    __shared__ int s_cnt, s_st0, s_st1;

    const int tid = threadIdx.x;
    const int blk = blockIdx.x;
    if (tid == 0) s_isbf = detect_bf16(Wfc);
    __syncthreads();
    const int isbf = s_isbf;
    unsigned short* U = (unsigned short*)(ws + U_BASE);

    // ---- Stage 1a: pack W1/W2/Wf1/Wf2 -> bf16 [320][320] (all blocks,
    //                4 elements per thread: 320*320*4 = 409600) ----
    {
        const int g0 = blk * 1280 + tid * 4;
        const int mi = g0 / 102400;
        const int rem = g0 - mi * 102400;
        const int row = rem / 320, k0 = rem - row * 320;
        const void* src = (mi == 0) ? W1 : (mi == 1) ? W2 : (mi == 2) ? Wf1 : Wf2;
        ushort4 o;
        unsigned short* op = (unsigned short*)&o;
        #pragma unroll
        for (int j = 0; j < 4; ++j) {
            float v = (row < 300 && k0 + j < 300) ? ldf(src, row * 300 + k0 + j, isbf) : 0.f;
            op[j] = f2bf(v);
        }
        *(ushort4*)(U + WPACK + g0) = o;
    }
    // ---- Stage 1b: rep = elu(X@Wfc^T + bfc)  (tid<256, all 320 blocks) ----
    if (tid < 256) {
        const int w = tid >> 6, l = tid & 63;
        const int mt = blk / 5, nt = blk % 5;
        const int m0 = mt * 16, lm = l & 15, koff = (l >> 4) * 8;
        const int nrow = nt * 64 + w * 16 + lm;          // 0..319
        const int bval = nrow < 300;
        const int ncl = bval ? nrow : 0;
        f32x4 acc = {0.f, 0.f, 0.f, 0.f};
        if (isbf) {
            const unsigned short* Xp = (const unsigned short*)Xv + (m0 + lm) * 300;
            #pragma unroll
            for (int ks = 0; ks < 10; ++ks) {
                short8 a = load8bf(Xp, ks*32 + koff, 300, 1);
                short8 b = loadB(Wfc, ncl, ks*32 + koff, 1, bval);
                acc = __builtin_amdgcn_mfma_f32_16x16x32_bf16(a, b, acc, 0, 0, 0);
            }
        } else {
            const float* Xp = (const float*)Xv + (m0 + lm) * 300;
            #pragma unroll
            for (int ks = 0; ks < 10; ++ks) {
                float t[8]; load8f(Xp, ks*32 + koff, 300, 1, t);
                short8 a = pack8(t);
                short8 b = loadB(Wfc, ncl, ks*32 + koff, 0, bval);
                acc = __builtin_amdgcn_mfma_f32_16x16x32_bf16(a, b, acc, 0, 0, 0);
            }
        }
        if (bval) {
            float bb = ldf(bfc, nrow, isbf);
            #pragma unroll
            for (int r = 0; r < 4; ++r) {
                int mg = m0 + (l >> 4) * 4 + r;
                float v = acc[r] + bb;
                v = v > 0.f ? v : (__expf(v) - 1.f);
                ws[OFF_REP + mg * 300 + nrow] = v;
                U[REPB + mg * 320 + nrow] = f2bf(v);
            }
        } else {
            #pragma unroll
            for (int r = 0; r < 4; ++r) {
                int mg = m0 + (l >> 4) * 4 + r;
                U[REPB + mg * 320 + nrow] = 0;
            }
        }
    }
    gbar(ws, 0, blk);

    // ---- Stage 2: dep/head = rep @ {W1,W2}^T; dep -> exd = exp(0.4*(dep+b1)).
    //               640 units on 320 blocks: u = blk, blk+320. ----
    if (tid < 256) {
        const int w = tid >> 6, l = tid & 63;
        const int lm = l & 15, koff = (l >> 4) * 8;
        #pragma unroll
        for (int u = blk; u < 640; u += 320) {
            const int mt = u / 10, nt = u % 10;
            const int m0 = mt * 16;
            const int ng = nt * 64 + w * 16 + lm;            // 0..639
            const int wsel = ng < 320;
            const int wrow = wsel ? ng : ng - 320;           // packed rows >=300 are zero
            const unsigned short* ap = U + REPB + (m0 + lm) * 320 + koff;
            const unsigned short* bp = U + (wsel ? WP1 : WP2) + wrow * 320 + koff;
            f32x4 acc = {0.f, 0.f, 0.f, 0.f};
            #pragma unroll
            for (int ks = 0; ks < 10; ++ks) {
                short8 a = *(const short8*)(ap + ks * 32);
                short8 b = *(const short8*)(bp + ks * 32);
                acc = __builtin_amdgcn_mfma_f32_16x16x32_bf16(a, b, acc, 0, 0, 0);
            }
            if (ng < 300) {
                float bb = ldf(b1v, ng, isbf);
                #pragma unroll
                for (int r = 0; r < 4; ++r) {
                    int mg = m0 + (l >> 4) * 4 + r;
                    ws[OFF_DEP + mg * 300 + ng] = __expf(0.4f * (acc[r] + bb));
                }
            } else if (ng >= 320 && ng < 620) {
                #pragma unroll
                for (int r = 0; r < 4; ++r) {
                    int mg = m0 + (l >> 4) * 4 + r;
                    ws[OFF_HEAD + mg * 300 + (ng - 320)] = acc[r];
                }
            }
        }
    }
    gbar(ws, 1, blk);

    // ---- Stage 3: attention, 512 i-pair units on 320 blocks (u=blk, blk+320);
    //               SKIP rows with rep_mask[i]=0 (outputs zeroed by final mask;
    //               mm3 epilogue guarded so poisoned attn rows never read). ----
    for (int u = blk; u < 512; u += 320) {
        const int b = u >> 7;
        const int tile = u & 127;
        const int uu = tile >> 1;
        const int i0 = (tile & 1) ? (254 - 2 * uu) : (2 * uu);
        const int base = b * 256;
        const int mv0 = mask[base + i0] != 0;
        const int mv1 = mask[base + i0 + 1] != 0;
        __syncthreads();                      // protect vlist across iterations
        if ((mv0 | mv1) && tid < 64) {
            int basec = 0, st0 = 0, st1 = 0;
            #pragma unroll
            for (int c = 0; c < 4; ++c) {
                const int j = c * 64 + tid;
                const int mv = mask[base + j] != 0;
                unsigned long long bal = __ballot(mv);
                int pos = basec + __popcll(bal & ((1ull << tid) - 1ull));
                if (mv) vlist[pos] = (unsigned short)j;
                if (tid == 0) {
                    int lim0 = i0 - c * 64;
                    if (lim0 >= 0)
                        st0 += __popcll(bal & (lim0 >= 63 ? ~0ull : ((2ull << lim0) - 1ull)));
                    int lim1 = i0 + 1 - c * 64;
                    if (lim1 >= 0)
                        st1 += __popcll(bal & (lim1 >= 63 ? ~0ull : ((2ull << lim1) - 1ull)));
                }
                basec += __popcll(bal);
            }
            if (tid == 0) { s_cnt = basec; s_st0 = st0; s_st1 = st1; }
        }
        __syncthreads();
        const int d = tid;
        if (d >= 300) {
            U[ATB + (base + i0) * 320 + d] = 0;
            U[ATB + (base + i0 + 1) * 320 + d] = 0;
        } else if (mv0 & mv1) {
            const int cnt = s_cnt, st0 = s_st0, st1 = s_st1;
            const float* headp = ws + OFF_HEAD;
            const float hv0 = headp[(base + i0) * Dx + d];
            const float hv1 = headp[(base + i0 + 1) * Dx + d];
            const float pw0 = __expf(0.4f * hv0);
            const float pw1 = __expf(0.4f * hv1);
            const float* ep = ws + OFF_DEP + base * Dx + d;
            const float* rp = ws + OFF_REP + base * Dx + d;
            float s0 = 0.f, r0 = 0.f, s1 = 0.f, r1 = 0.f;
            if (st1 > st0) {
                const int j = vlist[st0];
                float ex = ep[j * Dx];
                float rv = rp[j * Dx];
                float u0 = fmaf(ex, pw0, 1.0f);
                float e0 = __expf(-10.0f * __builtin_amdgcn_rcpf(u0));
                s0 += e0; r0 = fmaf(e0, rv, r0);
            }
            #pragma unroll 4
            for (int t = st1; t < cnt; ++t) {
                const int j = vlist[t];
                float ex = ep[j * Dx];
                float rv = rp[j * Dx];
                float u0 = fmaf(ex, pw0, 1.0f);
                float u1 = fmaf(ex, pw1, 1.0f);
                float e0 = __expf(-10.0f * __builtin_amdgcn_rcpf(u0));
                float e1 = __expf(-10.0f * __builtin_amdgcn_rcpf(u1));
                s0 += e0; r0 = fmaf(e0, rv, r0);
                s1 += e1; r1 = fmaf(e1, rv, r1);
            }
            const float den0 = s0 + (s0 == 0.f ? 1.f : 0.f) + 1e-20f;
            const float den1 = s1 + (s1 == 0.f ? 1.f : 0.f) + 1e-20f;
            const float a0 = r0 / den0, a1 = r1 / den1;
            ws[OFF_ATTN + (base + i0) * Dx + d]     = a0;
            ws[OFF_ATTN + (base + i0 + 1) * Dx + d] = a1;
            U[ATB + (base + i0) * 320 + d]     = f2bf(a0);
            U[ATB + (base + i0 + 1) * 320 + d] = f2bf(a1);
        } else if (mv0 | mv1) {
            const int cnt = s_cnt;
            const int ia  = mv0 ? i0 : (i0 + 1);
            const int sta = mv0 ? s_st0 : s_st1;
            const float hv = (ws + OFF_HEAD)[(base + ia) * Dx + d];
            const float pw = __expf(0.4f * hv);
            const float* ep = ws + OFF_DEP + base * Dx + d;
            const float* rp = ws + OFF_REP + base * Dx + d;
            float s = 0.f, r = 0.f;
            #pragma unroll 4
            for (int t = sta; t < cnt; ++t) {
                const int j = vlist[t];
                float ex = ep[j * Dx];
                float rv = rp[j * Dx];
                float u0 = fmaf(ex, pw, 1.0f);
                float e  = __expf(-10.0f * __builtin_amdgcn_rcpf(u0));
                s += e; r = fmaf(e, rv, r);
            }
            const float den = s + (s == 0.f ? 1.f : 0.f) + 1e-20f;
            const float a = r / den;
            ws[OFF_ATTN + (base + ia) * Dx + d] = a;
            U[ATB + (base + ia) * 320 + d] = f2bf(a);
        }
    }
    gbar(ws, 2, blk);

    // ---- Stage 4: gate = sigmoid(rep@Wf1^T + attn@Wf2^T + bf); blend; mask. ----
    if (tid < 256) {
        const int w = tid >> 6, l = tid & 63;
        const int mt = blk / 5, nt = blk % 5;
        const int m0 = mt * 16, lm = l & 15, koff = (l >> 4) * 8;
        const int nrow = nt * 64 + w * 16 + lm;          // 0..319 (rows >=300 zero)
        const unsigned short* a1p = U + REPB + (m0 + lm) * 320 + koff;
        const unsigned short* a2p = U + ATB  + (m0 + lm) * 320 + koff;
        const unsigned short* b1p = U + WPF1 + nrow * 320 + koff;
        const unsigned short* b2p = U + WPF2 + nrow * 320 + koff;
        f32x4 acc = {0.f, 0.f, 0.f, 0.f};
        #pragma unroll
        for (int ks = 0; ks < 10; ++ks) {
            short8 a = *(const short8*)(a1p + ks * 32);
            short8 b = *(const short8*)(b1p + ks * 32);
            acc = __builtin_amdgcn_mfma_f32_16x16x32_bf16(a, b, acc, 0, 0, 0);
        }
        #pragma unroll
        for (int ks = 0; ks < 10; ++ks) {
            short8 a = *(const short8*)(a2p + ks * 32);
            short8 b = *(const short8*)(b2p + ks * 32);
            acc = __builtin_amdgcn_mfma_f32_16x16x32_bf16(a, b, acc, 0, 0, 0);
        }
        if (nrow < 300) {
            float bb = ldf(bfv, nrow, isbf);
            #pragma unroll
            for (int r = 0; r < 4; ++r) {
                int mg = m0 + (l >> 4) * 4 + r;
                float res = 0.f;
                if (mask[mg]) {
                    float gp = acc[r] + bb;
                    float gate = 1.0f / (1.0f + __expf(-gp));
                    float rv = ws[OFF_REP  + mg * 300 + nrow];
                    float av = ws[OFF_ATTN + mg * 300 + nrow];
                    res = gate * rv + (1.0f - gate) * av;
                }
                if (isbf) ((__hip_bfloat16*)outv)[mg * 300 + nrow] = __float2bfloat16(res);
                else      ((float*)outv)[mg * 300 + nrow] = res;
            }
        }
    }
}

extern "C" void kernel_launch(void* const* d_in, const int* in_sizes, int n_in,
                              void* d_out, int out_size, void* d_ws, size_t ws_size,
                              hipStream_t stream) {
    const void* X   = d_in[0];
    const int*  msk = (const int*)d_in[1];
    const void* Wfc = d_in[2];
    const void* bfc = d_in[3];
    const void* W1  = d_in[4];
    const void* W2  = d_in[5];
    const void* b1  = d_in[6];
    const void* Wf1 = d_in[7];
    const void* Wf2 = d_in[8];
    const void* bfv = d_in[9];
    float* ws = (float*)d_ws;

    // zero the tree-barrier state (3 barriers x 8 KB)
    hipMemsetAsync((char*)d_ws + (size_t)SYNC_FOFF * sizeof(float), 0, 24576, stream);

    hipLaunchKernelGGL(k_fused, dim3(NBLK), dim3(320), 0, stream,
                       X, msk, Wfc, bfc, W1, W2, b1, Wf1, Wf2, bfv, ws, d_out);
}

// Round 5
// 144.753 us; speedup vs baseline: 3.2915x; 1.1346x over previous
//
#include <hip/hip_runtime.h>
#include <hip/hip_bf16.h>

#define Dx 300

// float-offsets into ws
#define OFF_REP    0
#define OFF_DEP    307200      // holds exd = exp(0.4*(dep+b1))
#define OFF_HEAD   614400
#define OFF_ATTN   921600
// ushort arrays at U = (ushort*)(ws + 1228800): zero-padded
#define U_BASE     1228800
#define REPB       0           // [1024][320]
#define ATB        327680      // [1024][320]
#define WPACK      655360      // 4 x [320][320]: W1, W2, Wf1, Wf2 (contiguous)
#define WP1        655360
#define WP2        757760
#define WPF1       860160
#define WPF2       962560
// software grid-barrier state (zeroed by hipMemsetAsync before launch)
#define SYNC_FOFF  2000000     // float offset, 8 MB into ws — clear of all data

#define NBLK 320

typedef __attribute__((ext_vector_type(8))) short short8;
typedef __attribute__((ext_vector_type(4))) float f32x4;

union S8 { unsigned int u[4]; unsigned short s[8]; short8 v; };

__device__ __forceinline__ float bf2f(unsigned short u) {
    union { unsigned int i; float f; } v; v.i = ((unsigned int)u) << 16; return v.f;
}
__device__ __forceinline__ unsigned short f2bf(float x) {   // round-half-up
    union { float f; unsigned int i; } u; u.f = x;
    return (unsigned short)((u.i + 0x8000u) >> 16);
}
__device__ __forceinline__ int detect_bf16(const void* w) {
    const unsigned short* u = (const unsigned short*)w;
    int ok = 1;
    #pragma unroll
    for (int t = 0; t < 64; ++t) { float v = bf2f(u[t]); ok &= (fabsf(v) < 1.0f) ? 1 : 0; }
    return ok;
}
__device__ __forceinline__ float ldf(const void* p, int idx, int isbf) {
    return isbf ? bf2f(((const unsigned short*)p)[idx]) : ((const float*)p)[idx];
}

__device__ __forceinline__ void load8f(const float* rowp, int kb, int kmax,
                                       int valid, float* x) {
    if (valid && kb + 8 <= kmax) {
        float4 a = *(const float4*)(rowp + kb);
        float4 b = *(const float4*)(rowp + kb + 4);
        x[0]=a.x; x[1]=a.y; x[2]=a.z; x[3]=a.w;
        x[4]=b.x; x[5]=b.y; x[6]=b.z; x[7]=b.w;
    } else {
        #pragma unroll
        for (int j = 0; j < 8; ++j) {
            int k = kb + j;
            x[j] = (valid && k < kmax) ? rowp[k] : 0.f;
        }
    }
}
__device__ __forceinline__ short8 pack8(const float* x) {
    S8 H;
    #pragma unroll
    for (int p = 0; p < 4; ++p) {
        union { float f; unsigned int i; } a, b;
        a.f = x[2*p]; b.f = x[2*p+1];
        H.u[p] = ((a.i + 0x8000u) >> 16) | ((b.i + 0x8000u) & 0xFFFF0000u);
    }
    return H.v;
}
__device__ __forceinline__ short8 load8bf(const unsigned short* rowp, int kb,
                                          int kmax, int valid) {
    S8 R;
    if (valid && kb + 8 <= kmax) {
        ushort4 a = *(const ushort4*)(rowp + kb);
        ushort4 b = *(const ushort4*)(rowp + kb + 4);
        R.s[0]=a.x; R.s[1]=a.y; R.s[2]=a.z; R.s[3]=a.w;
        R.s[4]=b.x; R.s[5]=b.y; R.s[6]=b.z; R.s[7]=b.w;
    } else {
        #pragma unroll
        for (int j = 0; j < 8; ++j) {
            int k = kb + j;
            R.s[j] = (valid && k < kmax) ? rowp[k] : (unsigned short)0;
        }
    }
    return R.v;
}
__device__ __forceinline__ short8 loadB(const void* W, int row, int kb, int isbf,
                                        int valid) {
    if (isbf) return load8bf((const unsigned short*)W + row * 300, kb, 300, valid);
    float t[8];
    load8f((const float*)W + row * 300, kb, 300, valid, t);
    return pack8(t);
}

// ---------------------------------------------------------------------------
// Grid barrier v4 — cache-maintenance-thinned.
// Theory: rounds 2-4 showed per-arrival RELEASE (vmcnt+buffer_wbl2 = whole-L2
// writeback walk) x 320 blocks x 3 barriers, serialized per XCD, is the idle
// cost. Fix: only the LAST block on each XCD (discovered at runtime via
// s_getreg(HW_REG_XCC_ID), HW-verified on gfx950) issues the RELEASE flush:
// 8 wbl2/barrier instead of 320. Exit-side ACQUIRE (buffer_inv) is dropped
// entirely: the dispatch acquire already invalidated L2 at launch, and no
// XCD caches a line of an inter-stage buffer before the barrier publishing
// it — so consumer L2s can hold no stale copy; first touch misses to L3,
// which the 8 flushes made fresh.
// All spins are RELAXED agent loads (sc1, no cache maintenance). Poll fan-out
// kept small: members poll per-XCD exit flags (<=~40 readers/line), locals-
// last poll fin (<=8 readers). Bounded spins: a lost block => visible verify
// failure, never a hung container.
// ---------------------------------------------------------------------------
#define AG __HIP_MEMORY_SCOPE_AGENT
__device__ __forceinline__ int xcd_id() {
    int x;
    asm volatile("s_getreg_b32 %0, hwreg(HW_REG_XCC_ID)" : "=s"(x));
    return x & 7;
}
__device__ __forceinline__ void spin_relaxed(int* flag) {
    int t = 0;
    while (__hip_atomic_load(flag, __ATOMIC_RELAXED, AG) == 0) {
        __builtin_amdgcn_s_sleep(2);
        if (++t > 200000) break;                 // ~25 ms escape hatch
    }
    asm volatile("" ::: "memory");               // no load hoisting above spin
}

__device__ __forceinline__ void gbar(float* ws, int idx, int nblk) {
    __syncthreads();   // drains this block's stores to L2 (compiler vmcnt(0))
    if (threadIdx.x == 0) {
        int* base  = (int*)(ws + SYNC_FOFF) + idx * 2048;  // 8 KB per barrier
        int* gcnt  = base + 0 * 64;
        int* flag1 = base + 1 * 64;
        int* nx    = base + 2 * 64;
        int* done  = base + 3 * 64;
        int* fin   = base + 4 * 64;
        int* xcnt  = base + 8 * 64;    // [8], 256 B apart
        int* xcnt2 = base + 16 * 64;   // [8]
        int* xfin  = base + 24 * 64;   // [8]
        const int xid = xcd_id();

        // ---- phase 1: register presence, establish "all arrived" ----
        __hip_atomic_fetch_add(xcnt + xid * 64, 1, __ATOMIC_RELAXED, AG);
        asm volatile("s_waitcnt vmcnt(0)" ::: "memory");  // xcnt before gcnt
        int g = __hip_atomic_fetch_add(gcnt, 1, __ATOMIC_RELAXED, AG);
        if (g == nblk - 1) {
            int n = 0;
            #pragma unroll
            for (int k = 0; k < 8; ++k)
                n += (__hip_atomic_load(xcnt + k * 64, __ATOMIC_RELAXED, AG) != 0);
            __hip_atomic_store(nx, n, __ATOMIC_RELAXED, AG);
            asm volatile("s_waitcnt vmcnt(0)" ::: "memory");  // nx before flag1
            __hip_atomic_store(flag1, 1, __ATOMIC_RELAXED, AG);
        } else {
            spin_relaxed(flag1);
        }

        // ---- phase 2: per-XCD local-last election; 8 flushes total ----
        int tot = __hip_atomic_load(xcnt + xid * 64, __ATOMIC_RELAXED, AG);
        int t2  = __hip_atomic_fetch_add(xcnt2 + xid * 64, 1, __ATOMIC_RELAXED, AG);
        if (t2 == tot - 1) {                     // last block on this XCD
            int nxv = __hip_atomic_load(nx, __ATOMIC_RELAXED, AG);
            // RELEASE: vmcnt drain + buffer_wbl2 (flush this XCD's L2) + add
            int d = __hip_atomic_fetch_add(done, 1, __ATOMIC_RELEASE, AG);
            if (d == nxv - 1) {
                __hip_atomic_store(fin, 1, __ATOMIC_RELEASE, AG);
            } else {
                spin_relaxed(fin);
            }
            __hip_atomic_store(xfin + xid * 64, 1, __ATOMIC_RELAXED, AG);
        } else {
            spin_relaxed(xfin + xid * 64);
        }
    }
    __syncthreads();
}

// ---------------------------------------------------------------------------
// Fused DiSA forward: mm1+pack -> bar -> mm2 -> bar -> attn -> bar -> mm3.
// grid 320 x 320 threads (5 waves).
// ---------------------------------------------------------------------------
__global__ __launch_bounds__(320, 4) void k_fused(
        const void* __restrict__ Xv, const int* __restrict__ mask,
        const void* __restrict__ Wfc, const void* __restrict__ bfc,
        const void* __restrict__ W1,  const void* __restrict__ W2,
        const void* __restrict__ b1v, const void* __restrict__ Wf1,
        const void* __restrict__ Wf2, const void* __restrict__ bfv,
        float* __restrict__ ws, void* __restrict__ outv) {
    __shared__ int s_isbf;
    __shared__ unsigned short vlist[256];
    __shared__ int s_cnt, s_st0, s_st1;

    const int tid = threadIdx.x;
    const int blk = blockIdx.x;
    if (tid == 0) s_isbf = detect_bf16(Wfc);
    __syncthreads();
    const int isbf = s_isbf;
    unsigned short* U = (unsigned short*)(ws + U_BASE);

    // ---- Stage 1a: pack W1/W2/Wf1/Wf2 -> bf16 [320][320] (all blocks,
    //                4 elements per thread: 320*320*4 = 409600) ----
    {
        const int g0 = blk * 1280 + tid * 4;
        const int mi = g0 / 102400;
        const int rem = g0 - mi * 102400;
        const int row = rem / 320, k0 = rem - row * 320;
        const void* src = (mi == 0) ? W1 : (mi == 1) ? W2 : (mi == 2) ? Wf1 : Wf2;
        ushort4 o;
        unsigned short* op = (unsigned short*)&o;
        #pragma unroll
        for (int j = 0; j < 4; ++j) {
            float v = (row < 300 && k0 + j < 300) ? ldf(src, row * 300 + k0 + j, isbf) : 0.f;
            op[j] = f2bf(v);
        }
        *(ushort4*)(U + WPACK + g0) = o;
    }
    // ---- Stage 1b: rep = elu(X@Wfc^T + bfc)  (tid<256, all 320 blocks) ----
    if (tid < 256) {
        const int w = tid >> 6, l = tid & 63;
        const int mt = blk / 5, nt = blk % 5;
        const int m0 = mt * 16, lm = l & 15, koff = (l >> 4) * 8;
        const int nrow = nt * 64 + w * 16 + lm;          // 0..319
        const int bval = nrow < 300;
        const int ncl = bval ? nrow : 0;
        f32x4 acc = {0.f, 0.f, 0.f, 0.f};
        if (isbf) {
            const unsigned short* Xp = (const unsigned short*)Xv + (m0 + lm) * 300;
            #pragma unroll
            for (int ks = 0; ks < 10; ++ks) {
                short8 a = load8bf(Xp, ks*32 + koff, 300, 1);
                short8 b = loadB(Wfc, ncl, ks*32 + koff, 1, bval);
                acc = __builtin_amdgcn_mfma_f32_16x16x32_bf16(a, b, acc, 0, 0, 0);
            }
        } else {
            const float* Xp = (const float*)Xv + (m0 + lm) * 300;
            #pragma unroll
            for (int ks = 0; ks < 10; ++ks) {
                float t[8]; load8f(Xp, ks*32 + koff, 300, 1, t);
                short8 a = pack8(t);
                short8 b = loadB(Wfc, ncl, ks*32 + koff, 0, bval);
                acc = __builtin_amdgcn_mfma_f32_16x16x32_bf16(a, b, acc, 0, 0, 0);
            }
        }
        if (bval) {
            float bb = ldf(bfc, nrow, isbf);
            #pragma unroll
            for (int r = 0; r < 4; ++r) {
                int mg = m0 + (l >> 4) * 4 + r;
                float v = acc[r] + bb;
                v = v > 0.f ? v : (__expf(v) - 1.f);
                ws[OFF_REP + mg * 300 + nrow] = v;
                U[REPB + mg * 320 + nrow] = f2bf(v);
            }
        } else {
            #pragma unroll
            for (int r = 0; r < 4; ++r) {
                int mg = m0 + (l >> 4) * 4 + r;
                U[REPB + mg * 320 + nrow] = 0;
            }
        }
    }
    gbar(ws, 0, NBLK);

    // ---- Stage 2: dep/head = rep @ {W1,W2}^T; dep -> exd = exp(0.4*(dep+b1)).
    //               640 units on 320 blocks: u = blk, blk+320. ----
    if (tid < 256) {
        const int w = tid >> 6, l = tid & 63;
        const int lm = l & 15, koff = (l >> 4) * 8;
        #pragma unroll
        for (int u = blk; u < 640; u += 320) {
            const int mt = u / 10, nt = u % 10;
            const int m0 = mt * 16;
            const int ng = nt * 64 + w * 16 + lm;            // 0..639
            const int wsel = ng < 320;
            const int wrow = wsel ? ng : ng - 320;           // packed rows >=300 are zero
            const unsigned short* ap = U + REPB + (m0 + lm) * 320 + koff;
            const unsigned short* bp = U + (wsel ? WP1 : WP2) + wrow * 320 + koff;
            f32x4 acc = {0.f, 0.f, 0.f, 0.f};
            #pragma unroll
            for (int ks = 0; ks < 10; ++ks) {
                short8 a = *(const short8*)(ap + ks * 32);
                short8 b = *(const short8*)(bp + ks * 32);
                acc = __builtin_amdgcn_mfma_f32_16x16x32_bf16(a, b, acc, 0, 0, 0);
            }
            if (ng < 300) {
                float bb = ldf(b1v, ng, isbf);
                #pragma unroll
                for (int r = 0; r < 4; ++r) {
                    int mg = m0 + (l >> 4) * 4 + r;
                    ws[OFF_DEP + mg * 300 + ng] = __expf(0.4f * (acc[r] + bb));
                }
            } else if (ng >= 320 && ng < 620) {
                #pragma unroll
                for (int r = 0; r < 4; ++r) {
                    int mg = m0 + (l >> 4) * 4 + r;
                    ws[OFF_HEAD + mg * 300 + (ng - 320)] = acc[r];
                }
            }
        }
    }
    gbar(ws, 1, NBLK);

    // ---- Stage 3: attention, 512 i-pair units on 320 blocks (u=blk, blk+320);
    //               SKIP rows with rep_mask[i]=0 (outputs zeroed by final mask;
    //               mm3 epilogue guarded so poisoned attn rows never read). ----
    for (int u = blk; u < 512; u += 320) {
        const int b = u >> 7;
        const int tile = u & 127;
        const int uu = tile >> 1;
        const int i0 = (tile & 1) ? (254 - 2 * uu) : (2 * uu);
        const int base = b * 256;
        const int mv0 = mask[base + i0] != 0;
        const int mv1 = mask[base + i0 + 1] != 0;
        __syncthreads();                      // protect vlist across iterations
        if ((mv0 | mv1) && tid < 64) {
            int basec = 0, st0 = 0, st1 = 0;
            #pragma unroll
            for (int c = 0; c < 4; ++c) {
                const int j = c * 64 + tid;
                const int mv = mask[base + j] != 0;
                unsigned long long bal = __ballot(mv);
                int pos = basec + __popcll(bal & ((1ull << tid) - 1ull));
                if (mv) vlist[pos] = (unsigned short)j;
                if (tid == 0) {
                    int lim0 = i0 - c * 64;
                    if (lim0 >= 0)
                        st0 += __popcll(bal & (lim0 >= 63 ? ~0ull : ((2ull << lim0) - 1ull)));
                    int lim1 = i0 + 1 - c * 64;
                    if (lim1 >= 0)
                        st1 += __popcll(bal & (lim1 >= 63 ? ~0ull : ((2ull << lim1) - 1ull)));
                }
                basec += __popcll(bal);
            }
            if (tid == 0) { s_cnt = basec; s_st0 = st0; s_st1 = st1; }
        }
        __syncthreads();
        const int d = tid;
        if (d >= 300) {
            U[ATB + (base + i0) * 320 + d] = 0;
            U[ATB + (base + i0 + 1) * 320 + d] = 0;
        } else if (mv0 & mv1) {
            const int cnt = s_cnt, st0 = s_st0, st1 = s_st1;
            const float* headp = ws + OFF_HEAD;
            const float hv0 = headp[(base + i0) * Dx + d];
            const float hv1 = headp[(base + i0 + 1) * Dx + d];
            const float pw0 = __expf(0.4f * hv0);
            const float pw1 = __expf(0.4f * hv1);
            const float* ep = ws + OFF_DEP + base * Dx + d;
            const float* rp = ws + OFF_REP + base * Dx + d;
            float s0 = 0.f, r0 = 0.f, s1 = 0.f, r1 = 0.f;
            if (st1 > st0) {
                const int j = vlist[st0];
                float ex = ep[j * Dx];
                float rv = rp[j * Dx];
                float u0 = fmaf(ex, pw0, 1.0f);
                float e0 = __expf(-10.0f * __builtin_amdgcn_rcpf(u0));
                s0 += e0; r0 = fmaf(e0, rv, r0);
            }
            #pragma unroll 4
            for (int t = st1; t < cnt; ++t) {
                const int j = vlist[t];
                float ex = ep[j * Dx];
                float rv = rp[j * Dx];
                float u0 = fmaf(ex, pw0, 1.0f);
                float u1 = fmaf(ex, pw1, 1.0f);
                float e0 = __expf(-10.0f * __builtin_amdgcn_rcpf(u0));
                float e1 = __expf(-10.0f * __builtin_amdgcn_rcpf(u1));
                s0 += e0; r0 = fmaf(e0, rv, r0);
                s1 += e1; r1 = fmaf(e1, rv, r1);
            }
            const float den0 = s0 + (s0 == 0.f ? 1.f : 0.f) + 1e-20f;
            const float den1 = s1 + (s1 == 0.f ? 1.f : 0.f) + 1e-20f;
            const float a0 = r0 / den0, a1 = r1 / den1;
            ws[OFF_ATTN + (base + i0) * Dx + d]     = a0;
            ws[OFF_ATTN + (base + i0 + 1) * Dx + d] = a1;
            U[ATB + (base + i0) * 320 + d]     = f2bf(a0);
            U[ATB + (base + i0 + 1) * 320 + d] = f2bf(a1);
        } else if (mv0 | mv1) {
            const int cnt = s_cnt;
            const int ia  = mv0 ? i0 : (i0 + 1);
            const int sta = mv0 ? s_st0 : s_st1;
            const float hv = (ws + OFF_HEAD)[(base + ia) * Dx + d];
            const float pw = __expf(0.4f * hv);
            const float* ep = ws + OFF_DEP + base * Dx + d;
            const float* rp = ws + OFF_REP + base * Dx + d;
            float s = 0.f, r = 0.f;
            #pragma unroll 4
            for (int t = sta; t < cnt; ++t) {
                const int j = vlist[t];
                float ex = ep[j * Dx];
                float rv = rp[j * Dx];
                float u0 = fmaf(ex, pw, 1.0f);
                float e  = __expf(-10.0f * __builtin_amdgcn_rcpf(u0));
                s += e; r = fmaf(e, rv, r);
            }
            const float den = s + (s == 0.f ? 1.f : 0.f) + 1e-20f;
            const float a = r / den;
            ws[OFF_ATTN + (base + ia) * Dx + d] = a;
            U[ATB + (base + ia) * 320 + d] = f2bf(a);
        }
    }
    gbar(ws, 2, NBLK);

    // ---- Stage 4: gate = sigmoid(rep@Wf1^T + attn@Wf2^T + bf); blend; mask. ----
    if (tid < 256) {
        const int w = tid >> 6, l = tid & 63;
        const int mt = blk / 5, nt = blk % 5;
        const int m0 = mt * 16, lm = l & 15, koff = (l >> 4) * 8;
        const int nrow = nt * 64 + w * 16 + lm;          // 0..319 (rows >=300 zero)
        const unsigned short* a1p = U + REPB + (m0 + lm) * 320 + koff;
        const unsigned short* a2p = U + ATB  + (m0 + lm) * 320 + koff;
        const unsigned short* b1p = U + WPF1 + nrow * 320 + koff;
        const unsigned short* b2p = U + WPF2 + nrow * 320 + koff;
        f32x4 acc = {0.f, 0.f, 0.f, 0.f};
        #pragma unroll
        for (int ks = 0; ks < 10; ++ks) {
            short8 a = *(const short8*)(a1p + ks * 32);
            short8 b = *(const short8*)(b1p + ks * 32);
            acc = __builtin_amdgcn_mfma_f32_16x16x32_bf16(a, b, acc, 0, 0, 0);
        }
        #pragma unroll
        for (int ks = 0; ks < 10; ++ks) {
            short8 a = *(const short8*)(a2p + ks * 32);
            short8 b = *(const short8*)(b2p + ks * 32);
            acc = __builtin_amdgcn_mfma_f32_16x16x32_bf16(a, b, acc, 0, 0, 0);
        }
        if (nrow < 300) {
            float bb = ldf(bfv, nrow, isbf);
            #pragma unroll
            for (int r = 0; r < 4; ++r) {
                int mg = m0 + (l >> 4) * 4 + r;
                float res = 0.f;
                if (mask[mg]) {
                    float gp = acc[r] + bb;
                    float gate = 1.0f / (1.0f + __expf(-gp));
                    float rv = ws[OFF_REP  + mg * 300 + nrow];
                    float av = ws[OFF_ATTN + mg * 300 + nrow];
                    res = gate * rv + (1.0f - gate) * av;
                }
                if (isbf) ((__hip_bfloat16*)outv)[mg * 300 + nrow] = __float2bfloat16(res);
                else      ((float*)outv)[mg * 300 + nrow] = res;
            }
        }
    }
}

extern "C" void kernel_launch(void* const* d_in, const int* in_sizes, int n_in,
                              void* d_out, int out_size, void* d_ws, size_t ws_size,
                              hipStream_t stream) {
    const void* X   = d_in[0];
    const int*  msk = (const int*)d_in[1];
    const void* Wfc = d_in[2];
    const void* bfc = d_in[3];
    const void* W1  = d_in[4];
    const void* W2  = d_in[5];
    const void* b1  = d_in[6];
    const void* Wf1 = d_in[7];
    const void* Wf2 = d_in[8];
    const void* bfv = d_in[9];
    float* ws = (float*)d_ws;

    // zero the barrier state (3 barriers x 8 KB)
    hipMemsetAsync((char*)d_ws + (size_t)SYNC_FOFF * sizeof(float), 0, 24576, stream);

    hipLaunchKernelGGL(k_fused, dim3(NBLK), dim3(320), 0, stream,
                       X, msk, Wfc, bfc, W1, W2, b1, Wf1, Wf2, bfv, ws, d_out);
}

// Round 6
// 133.856 us; speedup vs baseline: 3.5595x; 1.0814x over previous
//
#include <hip/hip_runtime.h>
#include <hip/hip_bf16.h>

#define Dx 300

// float-offsets into ws
#define OFF_REP    0
#define OFF_DEP    307200      // holds exd = exp(0.4*(dep+b1))
#define OFF_HEAD   614400
#define OFF_ATTN   921600
// ushort arrays at U = (ushort*)(ws + 1228800): zero-padded
#define U_BASE     1228800
#define REPB       0           // [1024][320]
#define ATB        327680      // [1024][320]
#define WPACK      655360      // 4 x [320][320]: W1, W2, Wf1, Wf2 (contiguous)
#define WP1        655360
#define WP2        757760
#define WPF1       860160
#define WPF2       962560
// software grid-barrier state (zeroed by hipMemsetAsync before launch)
#define SYNC_FOFF  2000000     // float offset, 8 MB into ws — clear of all data

#define NBLK 320

typedef __attribute__((ext_vector_type(8))) short short8;
typedef __attribute__((ext_vector_type(4))) float f32x4;

union S8 { unsigned int u[4]; unsigned short s[8]; short8 v; };

__device__ __forceinline__ float bf2f(unsigned short u) {
    union { unsigned int i; float f; } v; v.i = ((unsigned int)u) << 16; return v.f;
}
__device__ __forceinline__ unsigned short f2bf(float x) {   // round-half-up
    union { float f; unsigned int i; } u; u.f = x;
    return (unsigned short)((u.i + 0x8000u) >> 16);
}
__device__ __forceinline__ int detect_bf16(const void* w) {
    const unsigned short* u = (const unsigned short*)w;
    int ok = 1;
    #pragma unroll
    for (int t = 0; t < 64; ++t) { float v = bf2f(u[t]); ok &= (fabsf(v) < 1.0f) ? 1 : 0; }
    return ok;
}
__device__ __forceinline__ float ldf(const void* p, int idx, int isbf) {
    return isbf ? bf2f(((const unsigned short*)p)[idx]) : ((const float*)p)[idx];
}

// ---- write-through (L2-bypass, coherence-point) stores for inter-stage data.
// Data is agent-visible once vmcnt acks => no buffer_wbl2 needed anywhere.
__device__ __forceinline__ void st_wt_f32(float* p, float v) {
    asm volatile("global_store_dword %0, %1, off sc0 sc1"
                 :: "v"(p), "v"(v) : "memory");
}
__device__ __forceinline__ void st_wt_u16(unsigned short* p, unsigned short v) {
    unsigned int vv = v;
    asm volatile("global_store_short %0, %1, off sc0 sc1"
                 :: "v"(p), "v"(vv) : "memory");
}
__device__ __forceinline__ void st_wt_b64(void* p, unsigned long long v) {
    asm volatile("global_store_dwordx2 %0, %1, off sc0 sc1"
                 :: "v"(p), "v"(v) : "memory");
}

__device__ __forceinline__ void load8f(const float* rowp, int kb, int kmax,
                                       int valid, float* x) {
    if (valid && kb + 8 <= kmax) {
        float4 a = *(const float4*)(rowp + kb);
        float4 b = *(const float4*)(rowp + kb + 4);
        x[0]=a.x; x[1]=a.y; x[2]=a.z; x[3]=a.w;
        x[4]=b.x; x[5]=b.y; x[6]=b.z; x[7]=b.w;
    } else {
        #pragma unroll
        for (int j = 0; j < 8; ++j) {
            int k = kb + j;
            x[j] = (valid && k < kmax) ? rowp[k] : 0.f;
        }
    }
}
__device__ __forceinline__ short8 pack8(const float* x) {
    S8 H;
    #pragma unroll
    for (int p = 0; p < 4; ++p) {
        union { float f; unsigned int i; } a, b;
        a.f = x[2*p]; b.f = x[2*p+1];
        H.u[p] = ((a.i + 0x8000u) >> 16) | ((b.i + 0x8000u) & 0xFFFF0000u);
    }
    return H.v;
}
__device__ __forceinline__ short8 load8bf(const unsigned short* rowp, int kb,
                                          int kmax, int valid) {
    S8 R;
    if (valid && kb + 8 <= kmax) {
        ushort4 a = *(const ushort4*)(rowp + kb);
        ushort4 b = *(const ushort4*)(rowp + kb + 4);
        R.s[0]=a.x; R.s[1]=a.y; R.s[2]=a.z; R.s[3]=a.w;
        R.s[4]=b.x; R.s[5]=b.y; R.s[6]=b.z; R.s[7]=b.w;
    } else {
        #pragma unroll
        for (int j = 0; j < 8; ++j) {
            int k = kb + j;
            R.s[j] = (valid && k < kmax) ? rowp[k] : (unsigned short)0;
        }
    }
    return R.v;
}
__device__ __forceinline__ short8 loadB(const void* W, int row, int kb, int isbf,
                                        int valid) {
    if (isbf) return load8bf((const unsigned short*)W + row * 300, kb, 300, valid);
    float t[8];
    load8f((const float*)W + row * 300, kb, 300, valid, t);
    return pack8(t);
}

// ---------------------------------------------------------------------------
// Grid barrier v6 — zero cache maintenance, zero hot lines.
// Producers use sc0/sc1 write-through stores, so data is at the coherence
// point once vmcnt drains (done by __syncthreads) — NO buffer_wbl2 needed.
// Arrivals: relaxed adds on per-XCD lines (<=~40 contenders each, 8 lines in
// parallel — kills round-5's 320-RMWs-on-one-line serialization).
// First local arriver of each XCD = relay: polls the SUM of the 8 xcnt lines
// (only 8 pollers x 8 loads/round — kills the 319-pollers-one-line storm),
// then raises its per-XCD exit flag (<=40 pollers/line).
// No release/acquire anywhere: kernel-start dispatch-acquire invalidated all
// L2s; no consumer XCD caches an inter-stage line before its barrier.
// Bounded spins: a lost block => visible verify failure, never a hang.
// ---------------------------------------------------------------------------
#define AG __HIP_MEMORY_SCOPE_AGENT
__device__ __forceinline__ int xcd_id() {
    int x;
    asm volatile("s_getreg_b32 %0, hwreg(HW_REG_XCC_ID)" : "=s"(x));
    return x & 7;
}

__device__ __forceinline__ void gbar(float* ws, int idx) {
    __syncthreads();   // drains vmcnt(0): all sc1 stores acked at coherence pt
    if (threadIdx.x == 0) {
        int* base  = (int*)(ws + SYNC_FOFF) + idx * 2048;  // 8 KB per barrier
        int* xcnt  = base;                                 // 8 lines, 256 B apart
        int* xflag = base + 8 * 64;                        // 8 lines
        const int xid = xcd_id();
        int t2 = __hip_atomic_fetch_add(xcnt + xid * 64, 1, __ATOMIC_RELAXED, AG);
        if (t2 == 0) {                       // relay for this XCD
            int t = 0;
            for (;;) {
                int s = 0;
                #pragma unroll
                for (int k = 0; k < 8; ++k)
                    s += __hip_atomic_load(xcnt + k * 64, __ATOMIC_RELAXED, AG);
                if (s >= NBLK) break;
                __builtin_amdgcn_s_sleep(1);
                if (++t > 400000) break;     // escape hatch
            }
            __hip_atomic_store(xflag + xid * 64, 1, __ATOMIC_RELAXED, AG);
        } else {
            int t = 0;
            while (__hip_atomic_load(xflag + xid * 64, __ATOMIC_RELAXED, AG) == 0) {
                __builtin_amdgcn_s_sleep(2);
                if (++t > 400000) break;     // escape hatch
            }
        }
        asm volatile("" ::: "memory");
    }
    __syncthreads();
}

// ---------------------------------------------------------------------------
// Fused DiSA forward: mm1+pack -> bar -> mm2 -> bar -> attn -> bar -> mm3.
// grid 320 x 320 threads (5 waves).
// ---------------------------------------------------------------------------
__global__ __launch_bounds__(320, 4) void k_fused(
        const void* __restrict__ Xv, const int* __restrict__ mask,
        const void* __restrict__ Wfc, const void* __restrict__ bfc,
        const void* __restrict__ W1,  const void* __restrict__ W2,
        const void* __restrict__ b1v, const void* __restrict__ Wf1,
        const void* __restrict__ Wf2, const void* __restrict__ bfv,
        float* __restrict__ ws, void* __restrict__ outv) {
    __shared__ int s_isbf;
    __shared__ unsigned short vlist[256];
    __shared__ int s_cnt, s_st0, s_st1;

    const int tid = threadIdx.x;
    const int blk = blockIdx.x;
    if (tid == 0) s_isbf = detect_bf16(Wfc);
    __syncthreads();
    const int isbf = s_isbf;
    unsigned short* U = (unsigned short*)(ws + U_BASE);

    // ---- Stage 1a: pack W1/W2/Wf1/Wf2 -> bf16 [320][320] (all blocks,
    //                4 elements per thread: 320*320*4 = 409600) ----
    {
        const int g0 = blk * 1280 + tid * 4;
        const int mi = g0 / 102400;
        const int rem = g0 - mi * 102400;
        const int row = rem / 320, k0 = rem - row * 320;
        const void* src = (mi == 0) ? W1 : (mi == 1) ? W2 : (mi == 2) ? Wf1 : Wf2;
        union { ushort4 s4; unsigned long long u64; } o;
        unsigned short* op = (unsigned short*)&o.s4;
        #pragma unroll
        for (int j = 0; j < 4; ++j) {
            float v = (row < 300 && k0 + j < 300) ? ldf(src, row * 300 + k0 + j, isbf) : 0.f;
            op[j] = f2bf(v);
        }
        st_wt_b64(U + WPACK + g0, o.u64);
    }
    // ---- Stage 1b: rep = elu(X@Wfc^T + bfc)  (tid<256, all 320 blocks) ----
    if (tid < 256) {
        const int w = tid >> 6, l = tid & 63;
        const int mt = blk / 5, nt = blk % 5;
        const int m0 = mt * 16, lm = l & 15, koff = (l >> 4) * 8;
        const int nrow = nt * 64 + w * 16 + lm;          // 0..319
        const int bval = nrow < 300;
        const int ncl = bval ? nrow : 0;
        f32x4 acc = {0.f, 0.f, 0.f, 0.f};
        if (isbf) {
            const unsigned short* Xp = (const unsigned short*)Xv + (m0 + lm) * 300;
            #pragma unroll
            for (int ks = 0; ks < 10; ++ks) {
                short8 a = load8bf(Xp, ks*32 + koff, 300, 1);
                short8 b = loadB(Wfc, ncl, ks*32 + koff, 1, bval);
                acc = __builtin_amdgcn_mfma_f32_16x16x32_bf16(a, b, acc, 0, 0, 0);
            }
        } else {
            const float* Xp = (const float*)Xv + (m0 + lm) * 300;
            #pragma unroll
            for (int ks = 0; ks < 10; ++ks) {
                float t[8]; load8f(Xp, ks*32 + koff, 300, 1, t);
                short8 a = pack8(t);
                short8 b = loadB(Wfc, ncl, ks*32 + koff, 0, bval);
                acc = __builtin_amdgcn_mfma_f32_16x16x32_bf16(a, b, acc, 0, 0, 0);
            }
        }
        if (bval) {
            float bb = ldf(bfc, nrow, isbf);
            #pragma unroll
            for (int r = 0; r < 4; ++r) {
                int mg = m0 + (l >> 4) * 4 + r;
                float v = acc[r] + bb;
                v = v > 0.f ? v : (__expf(v) - 1.f);
                st_wt_f32(ws + OFF_REP + mg * 300 + nrow, v);
                st_wt_u16(U + REPB + mg * 320 + nrow, f2bf(v));
            }
        } else {
            #pragma unroll
            for (int r = 0; r < 4; ++r) {
                int mg = m0 + (l >> 4) * 4 + r;
                st_wt_u16(U + REPB + mg * 320 + nrow, 0);
            }
        }
    }
    gbar(ws, 0);

    // ---- Stage 2: dep/head = rep @ {W1,W2}^T; dep -> exd = exp(0.4*(dep+b1)).
    //               640 units on 320 blocks: u = blk, blk+320. ----
    if (tid < 256) {
        const int w = tid >> 6, l = tid & 63;
        const int lm = l & 15, koff = (l >> 4) * 8;
        #pragma unroll
        for (int u = blk; u < 640; u += 320) {
            const int mt = u / 10, nt = u % 10;
            const int m0 = mt * 16;
            const int ng = nt * 64 + w * 16 + lm;            // 0..639
            const int wsel = ng < 320;
            const int wrow = wsel ? ng : ng - 320;           // packed rows >=300 are zero
            const unsigned short* ap = U + REPB + (m0 + lm) * 320 + koff;
            const unsigned short* bp = U + (wsel ? WP1 : WP2) + wrow * 320 + koff;
            f32x4 acc = {0.f, 0.f, 0.f, 0.f};
            #pragma unroll
            for (int ks = 0; ks < 10; ++ks) {
                short8 a = *(const short8*)(ap + ks * 32);
                short8 b = *(const short8*)(bp + ks * 32);
                acc = __builtin_amdgcn_mfma_f32_16x16x32_bf16(a, b, acc, 0, 0, 0);
            }
            if (ng < 300) {
                float bb = ldf(b1v, ng, isbf);
                #pragma unroll
                for (int r = 0; r < 4; ++r) {
                    int mg = m0 + (l >> 4) * 4 + r;
                    st_wt_f32(ws + OFF_DEP + mg * 300 + ng,
                              __expf(0.4f * (acc[r] + bb)));
                }
            } else if (ng >= 320 && ng < 620) {
                #pragma unroll
                for (int r = 0; r < 4; ++r) {
                    int mg = m0 + (l >> 4) * 4 + r;
                    st_wt_f32(ws + OFF_HEAD + mg * 300 + (ng - 320), acc[r]);
                }
            }
        }
    }
    gbar(ws, 1);

    // ---- Stage 3: attention, 512 i-pair units on 320 blocks (u=blk, blk+320);
    //               SKIP rows with rep_mask[i]=0 (outputs zeroed by final mask;
    //               mm3 epilogue guarded so poisoned attn rows never read). ----
    for (int u = blk; u < 512; u += 320) {
        const int b = u >> 7;
        const int tile = u & 127;
        const int uu = tile >> 1;
        const int i0 = (tile & 1) ? (254 - 2 * uu) : (2 * uu);
        const int base = b * 256;
        const int mv0 = mask[base + i0] != 0;
        const int mv1 = mask[base + i0 + 1] != 0;
        __syncthreads();                      // protect vlist across iterations
        if ((mv0 | mv1) && tid < 64) {
            int basec = 0, st0 = 0, st1 = 0;
            #pragma unroll
            for (int c = 0; c < 4; ++c) {
                const int j = c * 64 + tid;
                const int mv = mask[base + j] != 0;
                unsigned long long bal = __ballot(mv);
                int pos = basec + __popcll(bal & ((1ull << tid) - 1ull));
                if (mv) vlist[pos] = (unsigned short)j;
                if (tid == 0) {
                    int lim0 = i0 - c * 64;
                    if (lim0 >= 0)
                        st0 += __popcll(bal & (lim0 >= 63 ? ~0ull : ((2ull << lim0) - 1ull)));
                    int lim1 = i0 + 1 - c * 64;
                    if (lim1 >= 0)
                        st1 += __popcll(bal & (lim1 >= 63 ? ~0ull : ((2ull << lim1) - 1ull)));
                }
                basec += __popcll(bal);
            }
            if (tid == 0) { s_cnt = basec; s_st0 = st0; s_st1 = st1; }
        }
        __syncthreads();
        const int d = tid;
        if (d >= 300) {
            st_wt_u16(U + ATB + (base + i0) * 320 + d, 0);
            st_wt_u16(U + ATB + (base + i0 + 1) * 320 + d, 0);
        } else if (mv0 & mv1) {
            const int cnt = s_cnt, st0 = s_st0, st1 = s_st1;
            const float* headp = ws + OFF_HEAD;
            const float hv0 = headp[(base + i0) * Dx + d];
            const float hv1 = headp[(base + i0 + 1) * Dx + d];
            const float pw0 = __expf(0.4f * hv0);
            const float pw1 = __expf(0.4f * hv1);
            const float* ep = ws + OFF_DEP + base * Dx + d;
            const float* rp = ws + OFF_REP + base * Dx + d;
            float s0 = 0.f, r0 = 0.f, s1 = 0.f, r1 = 0.f;
            if (st1 > st0) {
                const int j = vlist[st0];
                float ex = ep[j * Dx];
                float rv = rp[j * Dx];
                float u0 = fmaf(ex, pw0, 1.0f);
                float e0 = __expf(-10.0f * __builtin_amdgcn_rcpf(u0));
                s0 += e0; r0 = fmaf(e0, rv, r0);
            }
            #pragma unroll 4
            for (int t = st1; t < cnt; ++t) {
                const int j = vlist[t];
                float ex = ep[j * Dx];
                float rv = rp[j * Dx];
                float u0 = fmaf(ex, pw0, 1.0f);
                float u1 = fmaf(ex, pw1, 1.0f);
                float e0 = __expf(-10.0f * __builtin_amdgcn_rcpf(u0));
                float e1 = __expf(-10.0f * __builtin_amdgcn_rcpf(u1));
                s0 += e0; r0 = fmaf(e0, rv, r0);
                s1 += e1; r1 = fmaf(e1, rv, r1);
            }
            const float den0 = s0 + (s0 == 0.f ? 1.f : 0.f) + 1e-20f;
            const float den1 = s1 + (s1 == 0.f ? 1.f : 0.f) + 1e-20f;
            const float a0 = r0 / den0, a1 = r1 / den1;
            st_wt_f32(ws + OFF_ATTN + (base + i0) * Dx + d,     a0);
            st_wt_f32(ws + OFF_ATTN + (base + i0 + 1) * Dx + d, a1);
            st_wt_u16(U + ATB + (base + i0) * 320 + d,     f2bf(a0));
            st_wt_u16(U + ATB + (base + i0 + 1) * 320 + d, f2bf(a1));
        } else if (mv0 | mv1) {
            const int cnt = s_cnt;
            const int ia  = mv0 ? i0 : (i0 + 1);
            const int sta = mv0 ? s_st0 : s_st1;
            const float hv = (ws + OFF_HEAD)[(base + ia) * Dx + d];
            const float pw = __expf(0.4f * hv);
            const float* ep = ws + OFF_DEP + base * Dx + d;
            const float* rp = ws + OFF_REP + base * Dx + d;
            float s = 0.f, r = 0.f;
            #pragma unroll 4
            for (int t = sta; t < cnt; ++t) {
                const int j = vlist[t];
                float ex = ep[j * Dx];
                float rv = rp[j * Dx];
                float u0 = fmaf(ex, pw, 1.0f);
                float e  = __expf(-10.0f * __builtin_amdgcn_rcpf(u0));
                s += e; r = fmaf(e, rv, r);
            }
            const float den = s + (s == 0.f ? 1.f : 0.f) + 1e-20f;
            const float a = r / den;
            st_wt_f32(ws + OFF_ATTN + (base + ia) * Dx + d, a);
            st_wt_u16(U + ATB + (base + ia) * 320 + d, f2bf(a));
        }
    }
    gbar(ws, 2);

    // ---- Stage 4: gate = sigmoid(rep@Wf1^T + attn@Wf2^T + bf); blend; mask.
    //               Output written with normal stores (kernel-end flush). ----
    if (tid < 256) {
        const int w = tid >> 6, l = tid & 63;
        const int mt = blk / 5, nt = blk % 5;
        const int m0 = mt * 16, lm = l & 15, koff = (l >> 4) * 8;
        const int nrow = nt * 64 + w * 16 + lm;          // 0..319 (rows >=300 zero)
        const unsigned short* a1p = U + REPB + (m0 + lm) * 320 + koff;
        const unsigned short* a2p = U + ATB  + (m0 + lm) * 320 + koff;
        const unsigned short* b1p = U + WPF1 + nrow * 320 + koff;
        const unsigned short* b2p = U + WPF2 + nrow * 320 + koff;
        f32x4 acc = {0.f, 0.f, 0.f, 0.f};
        #pragma unroll
        for (int ks = 0; ks < 10; ++ks) {
            short8 a = *(const short8*)(a1p + ks * 32);
            short8 b = *(const short8*)(b1p + ks * 32);
            acc = __builtin_amdgcn_mfma_f32_16x16x32_bf16(a, b, acc, 0, 0, 0);
        }
        #pragma unroll
        for (int ks = 0; ks < 10; ++ks) {
            short8 a = *(const short8*)(a2p + ks * 32);
            short8 b = *(const short8*)(b2p + ks * 32);
            acc = __builtin_amdgcn_mfma_f32_16x16x32_bf16(a, b, acc, 0, 0, 0);
        }
        if (nrow < 300) {
            float bb = ldf(bfv, nrow, isbf);
            #pragma unroll
            for (int r = 0; r < 4; ++r) {
                int mg = m0 + (l >> 4) * 4 + r;
                float res = 0.f;
                if (mask[mg]) {
                    float gp = acc[r] + bb;
                    float gate = 1.0f / (1.0f + __expf(-gp));
                    float rv = ws[OFF_REP  + mg * 300 + nrow];
                    float av = ws[OFF_ATTN + mg * 300 + nrow];
                    res = gate * rv + (1.0f - gate) * av;
                }
                if (isbf) ((__hip_bfloat16*)outv)[mg * 300 + nrow] = __float2bfloat16(res);
                else      ((float*)outv)[mg * 300 + nrow] = res;
            }
        }
    }
}

extern "C" void kernel_launch(void* const* d_in, const int* in_sizes, int n_in,
                              void* d_out, int out_size, void* d_ws, size_t ws_size,
                              hipStream_t stream) {
    const void* X   = d_in[0];
    const int*  msk = (const int*)d_in[1];
    const void* Wfc = d_in[2];
    const void* bfc = d_in[3];
    const void* W1  = d_in[4];
    const void* W2  = d_in[5];
    const void* b1  = d_in[6];
    const void* Wf1 = d_in[7];
    const void* Wf2 = d_in[8];
    const void* bfv = d_in[9];
    float* ws = (float*)d_ws;

    // zero the barrier state (3 barriers x 8 KB)
    hipMemsetAsync((char*)d_ws + (size_t)SYNC_FOFF * sizeof(float), 0, 24576, stream);

    hipLaunchKernelGGL(k_fused, dim3(NBLK), dim3(320), 0, stream,
                       X, msk, Wfc, bfc, W1, W2, b1, Wf1, Wf2, bfv, ws, d_out);
}

// Round 7
// 127.225 us; speedup vs baseline: 3.7450x; 1.0521x over previous
//
#include <hip/hip_runtime.h>
#include <hip/hip_bf16.h>

#define Dx 300

// float-offsets into ws
#define REPF   0             // rep f32 [1024][300]          (K_A -> K_B, normal)
#define ED     307200        // float2 {exd, rep} [1024][300] (K_A -> K_B, normal)
#define HEADF  921600        // head f32 [1024][300]          (K_A -> K_B, normal)
#define U_BASE 1228800       // ushort region
#define REPB   0             // bf16 [1024][320]  (K_A intra: sc1)
#define ATB    327680        // bf16 [1024][320]  (K_B intra: sc1)
#define WPACK  655360        // 4 x [320][320] bf16: W1,W2,Wf1,Wf2 (K_A: sc1)
#define WP1    655360
#define WP2    757760
#define WPF1   860160
#define WPF2   962560
#define ATTNF  1761280       // attn f32 [1024][300] (K_B intra: sc1)
#define SYNC_FOFF 2100000    // barrier state (memset before launch)

typedef __attribute__((ext_vector_type(8))) short short8;
typedef __attribute__((ext_vector_type(4))) float f32x4;

union S8 { unsigned int u[4]; unsigned short s[8]; short8 v; };

__device__ __forceinline__ float bf2f(unsigned short u) {
    union { unsigned int i; float f; } v; v.i = ((unsigned int)u) << 16; return v.f;
}
__device__ __forceinline__ unsigned short f2bf(float x) {   // round-half-up
    union { float f; unsigned int i; } u; u.f = x;
    return (unsigned short)((u.i + 0x8000u) >> 16);
}
__device__ __forceinline__ int detect_bf16(const void* w) {
    const unsigned short* u = (const unsigned short*)w;
    int ok = 1;
    #pragma unroll
    for (int t = 0; t < 64; ++t) { float v = bf2f(u[t]); ok &= (fabsf(v) < 1.0f) ? 1 : 0; }
    return ok;
}
__device__ __forceinline__ float ldf(const void* p, int idx, int isbf) {
    return isbf ? bf2f(((const unsigned short*)p)[idx]) : ((const float*)p)[idx];
}

// ---- write-through stores (coherence point) — ONLY for intra-kernel edges
__device__ __forceinline__ void st_wt_f32(float* p, float v) {
    asm volatile("global_store_dword %0, %1, off sc0 sc1"
                 :: "v"(p), "v"(v) : "memory");
}
__device__ __forceinline__ void st_wt_u16(unsigned short* p, unsigned short v) {
    unsigned int vv = v;
    asm volatile("global_store_short %0, %1, off sc0 sc1"
                 :: "v"(p), "v"(vv) : "memory");
}
__device__ __forceinline__ void st_wt_u32(void* p, unsigned int v) {
    asm volatile("global_store_dword %0, %1, off sc0 sc1"
                 :: "v"(p), "v"(v) : "memory");
}

__device__ __forceinline__ void load8f(const float* rowp, int kb, int kmax,
                                       int valid, float* x) {
    if (valid && kb + 8 <= kmax) {
        float4 a = *(const float4*)(rowp + kb);
        float4 b = *(const float4*)(rowp + kb + 4);
        x[0]=a.x; x[1]=a.y; x[2]=a.z; x[3]=a.w;
        x[4]=b.x; x[5]=b.y; x[6]=b.z; x[7]=b.w;
    } else {
        #pragma unroll
        for (int j = 0; j < 8; ++j) {
            int k = kb + j;
            x[j] = (valid && k < kmax) ? rowp[k] : 0.f;
        }
    }
}
__device__ __forceinline__ short8 pack8(const float* x) {
    S8 H;
    #pragma unroll
    for (int p = 0; p < 4; ++p) {
        union { float f; unsigned int i; } a, b;
        a.f = x[2*p]; b.f = x[2*p+1];
        H.u[p] = ((a.i + 0x8000u) >> 16) | ((b.i + 0x8000u) & 0xFFFF0000u);
    }
    return H.v;
}
__device__ __forceinline__ short8 load8bf(const unsigned short* rowp, int kb,
                                          int kmax, int valid) {
    S8 R;
    if (valid && kb + 8 <= kmax) {
        ushort4 a = *(const ushort4*)(rowp + kb);
        ushort4 b = *(const ushort4*)(rowp + kb + 4);
        R.s[0]=a.x; R.s[1]=a.y; R.s[2]=a.z; R.s[3]=a.w;
        R.s[4]=b.x; R.s[5]=b.y; R.s[6]=b.z; R.s[7]=b.w;
    } else {
        #pragma unroll
        for (int j = 0; j < 8; ++j) {
            int k = kb + j;
            R.s[j] = (valid && k < kmax) ? rowp[k] : (unsigned short)0;
        }
    }
    return R.v;
}
__device__ __forceinline__ short8 loadB(const void* W, int row, int kb, int isbf,
                                        int valid) {
    if (isbf) return load8bf((const unsigned short*)W + row * 300, kb, 300, valid);
    float t[8];
    load8f((const float*)W + row * 300, kb, 300, valid, t);
    return pack8(t);
}

// ---------------------------------------------------------------------------
// Grid barrier (v6 structure): per-XCD arrival lines, relay-per-XCD poll,
// relaxed everywhere (producers on the guarded edges use sc1 write-through;
// __syncthreads drains vmcnt before arrival). Bounded spins.
// ---------------------------------------------------------------------------
#define AG __HIP_MEMORY_SCOPE_AGENT
__device__ __forceinline__ int xcd_id() {
    int x;
    asm volatile("s_getreg_b32 %0, hwreg(HW_REG_XCC_ID)" : "=s"(x));
    return x & 7;
}
__device__ __forceinline__ void gbar(float* ws, int idx, int nblk) {
    __syncthreads();
    if (threadIdx.x == 0) {
        int* base  = (int*)(ws + SYNC_FOFF) + idx * 2048;
        int* xcnt  = base;                 // 8 lines, 256 B apart
        int* xflag = base + 8 * 64;        // 8 lines
        const int xid = xcd_id();
        int t2 = __hip_atomic_fetch_add(xcnt + xid * 64, 1, __ATOMIC_RELAXED, AG);
        if (t2 == 0) {                     // relay for this XCD
            int t = 0;
            for (;;) {
                int s = 0;
                #pragma unroll
                for (int k = 0; k < 8; ++k)
                    s += __hip_atomic_load(xcnt + k * 64, __ATOMIC_RELAXED, AG);
                if (s >= nblk) break;
                __builtin_amdgcn_s_sleep(1);
                if (++t > 400000) break;
            }
            __hip_atomic_store(xflag + xid * 64, 1, __ATOMIC_RELAXED, AG);
        } else {
            int t = 0;
            while (__hip_atomic_load(xflag + xid * 64, __ATOMIC_RELAXED, AG) == 0) {
                __builtin_amdgcn_s_sleep(2);
                if (++t > 400000) break;
            }
        }
        asm volatile("" ::: "memory");
    }
    __syncthreads();
}

// ---------------------------------------------------------------------------
// K_A: pack + mm1(rep) -> bar -> mm2(exd/head). grid 640 x 320.
// ---------------------------------------------------------------------------
__global__ __launch_bounds__(320, 4) void k_a(
        const void* __restrict__ Xv, const void* __restrict__ Wfc,
        const void* __restrict__ bfc, const void* __restrict__ W1,
        const void* __restrict__ W2,  const void* __restrict__ b1v,
        const void* __restrict__ Wf1, const void* __restrict__ Wf2,
        float* __restrict__ ws) {
    __shared__ int s_isbf;
    const int tid = threadIdx.x;
    const int blk = blockIdx.x;
    if (tid == 0) s_isbf = detect_bf16(Wfc);
    __syncthreads();
    const int isbf = s_isbf;
    unsigned short* U = (unsigned short*)(ws + U_BASE);

    // ---- pack W1/W2/Wf1/Wf2 -> bf16 [320][320] (640 elems/block, 2/thread)
    {
        const int g0 = blk * 640 + tid * 2;
        const int mi = g0 / 102400;
        const int rem = g0 - mi * 102400;
        const int row = rem / 320, k0 = rem - row * 320;
        const void* src = (mi == 0) ? W1 : (mi == 1) ? W2 : (mi == 2) ? Wf1 : Wf2;
        float v0 = (row < 300 && k0     < 300) ? ldf(src, row * 300 + k0,     isbf) : 0.f;
        float v1 = (row < 300 && k0 + 1 < 300) ? ldf(src, row * 300 + k0 + 1, isbf) : 0.f;
        unsigned int pk = (unsigned int)f2bf(v0) | ((unsigned int)f2bf(v1) << 16);
        st_wt_u32(U + WPACK + g0, pk);
    }
    // ---- mm1: rep = elu(X@Wfc^T + bfc)  (blocks < 320, tid < 256)
    if (blk < 320 && tid < 256) {
        const int w = tid >> 6, l = tid & 63;
        const int mt = blk / 5, nt = blk % 5;
        const int m0 = mt * 16, lm = l & 15, koff = (l >> 4) * 8;
        const int nrow = nt * 64 + w * 16 + lm;          // 0..319
        const int bval = nrow < 300;
        const int ncl = bval ? nrow : 0;
        f32x4 acc = {0.f, 0.f, 0.f, 0.f};
        if (isbf) {
            const unsigned short* Xp = (const unsigned short*)Xv + (m0 + lm) * 300;
            #pragma unroll
            for (int ks = 0; ks < 10; ++ks) {
                short8 a = load8bf(Xp, ks*32 + koff, 300, 1);
                short8 b = loadB(Wfc, ncl, ks*32 + koff, 1, bval);
                acc = __builtin_amdgcn_mfma_f32_16x16x32_bf16(a, b, acc, 0, 0, 0);
            }
        } else {
            const float* Xp = (const float*)Xv + (m0 + lm) * 300;
            #pragma unroll
            for (int ks = 0; ks < 10; ++ks) {
                float t[8]; load8f(Xp, ks*32 + koff, 300, 1, t);
                short8 a = pack8(t);
                short8 b = loadB(Wfc, ncl, ks*32 + koff, 0, bval);
                acc = __builtin_amdgcn_mfma_f32_16x16x32_bf16(a, b, acc, 0, 0, 0);
            }
        }
        if (bval) {
            float bb = ldf(bfc, nrow, isbf);
            #pragma unroll
            for (int r = 0; r < 4; ++r) {
                int mg = m0 + (l >> 4) * 4 + r;
                float v = acc[r] + bb;
                v = v > 0.f ? v : (__expf(v) - 1.f);
                ws[REPF + mg * 300 + nrow] = v;                 // normal (K_B)
                ws[ED + (mg * 300 + nrow) * 2 + 1] = v;         // ed.y (K_B)
                st_wt_u16(U + REPB + mg * 320 + nrow, f2bf(v)); // sc1 (intra)
            }
        } else {
            #pragma unroll
            for (int r = 0; r < 4; ++r) {
                int mg = m0 + (l >> 4) * 4 + r;
                st_wt_u16(U + REPB + mg * 320 + nrow, 0);
            }
        }
    }
    gbar(ws, 0, 640);

    // ---- mm2: dep/head = rep @ {W1,W2}^T; one unit per block (u = blk)
    if (tid < 256) {
        const int w = tid >> 6, l = tid & 63;
        const int lm = l & 15, koff = (l >> 4) * 8;
        const int u = blk;
        const int mt = u / 10, nt = u % 10;
        const int m0 = mt * 16;
        const int ng = nt * 64 + w * 16 + lm;            // 0..639
        const int wsel = ng < 320;
        const int wrow = wsel ? ng : ng - 320;           // packed rows >=300 zero
        const unsigned short* ap = U + REPB + (m0 + lm) * 320 + koff;
        const unsigned short* bp = U + (wsel ? WP1 : WP2) + wrow * 320 + koff;
        f32x4 acc = {0.f, 0.f, 0.f, 0.f};
        #pragma unroll
        for (int ks = 0; ks < 10; ++ks) {
            short8 a = *(const short8*)(ap + ks * 32);
            short8 b = *(const short8*)(bp + ks * 32);
            acc = __builtin_amdgcn_mfma_f32_16x16x32_bf16(a, b, acc, 0, 0, 0);
        }
        if (ng < 300) {
            float bb = ldf(b1v, ng, isbf);
            #pragma unroll
            for (int r = 0; r < 4; ++r) {
                int mg = m0 + (l >> 4) * 4 + r;
                ws[ED + (mg * 300 + ng) * 2] = __expf(0.4f * (acc[r] + bb)); // ed.x
            }
        } else if (ng >= 320 && ng < 620) {
            #pragma unroll
            for (int r = 0; r < 4; ++r) {
                int mg = m0 + (l >> 4) * 4 + r;
                ws[HEADF + mg * 300 + (ng - 320)] = acc[r];
            }
        }
    }
}

// ---------------------------------------------------------------------------
// K_B: attn -> bar -> mm3. grid 512 x 320. ed float2 loads halve the hot loop.
// ---------------------------------------------------------------------------
__global__ __launch_bounds__(320, 4) void k_b(
        const int* __restrict__ mask, const void* __restrict__ Wfc,
        const void* __restrict__ bfv, float* __restrict__ ws,
        void* __restrict__ outv) {
    __shared__ int s_isbf;
    __shared__ unsigned short vlist[256];
    __shared__ int s_cnt, s_st0, s_st1;
    const int tid = threadIdx.x;
    const int blk = blockIdx.x;
    if (tid == 0) s_isbf = detect_bf16(Wfc);
    __syncthreads();
    const int isbf = s_isbf;
    unsigned short* U = (unsigned short*)(ws + U_BASE);

    // ---- attn: one i-pair unit per block; SKIP invalid-i rows (final mask
    //            zeroes them; mm3 epilogue guarded so they're never read) ----
    {
        const int b = blk >> 7;
        const int tile = blk & 127;
        const int uu = tile >> 1;
        const int i0 = (tile & 1) ? (254 - 2 * uu) : (2 * uu);
        const int base = b * 256;
        const int mv0 = mask[base + i0] != 0;
        const int mv1 = mask[base + i0 + 1] != 0;
        if ((mv0 | mv1) && tid < 64) {
            int basec = 0, st0 = 0, st1 = 0;
            #pragma unroll
            for (int c = 0; c < 4; ++c) {
                const int j = c * 64 + tid;
                const int mv = mask[base + j] != 0;
                unsigned long long bal = __ballot(mv);
                int pos = basec + __popcll(bal & ((1ull << tid) - 1ull));
                if (mv) vlist[pos] = (unsigned short)j;
                if (tid == 0) {
                    int lim0 = i0 - c * 64;
                    if (lim0 >= 0)
                        st0 += __popcll(bal & (lim0 >= 63 ? ~0ull : ((2ull << lim0) - 1ull)));
                    int lim1 = i0 + 1 - c * 64;
                    if (lim1 >= 0)
                        st1 += __popcll(bal & (lim1 >= 63 ? ~0ull : ((2ull << lim1) - 1ull)));
                }
                basec += __popcll(bal);
            }
            if (tid == 0) { s_cnt = basec; s_st0 = st0; s_st1 = st1; }
        }
        __syncthreads();
        const int d = tid;
        if (d >= 300) {
            st_wt_u16(U + ATB + (base + i0) * 320 + d, 0);
            st_wt_u16(U + ATB + (base + i0 + 1) * 320 + d, 0);
        } else if (mv0 & mv1) {
            const int cnt = s_cnt, st0 = s_st0, st1 = s_st1;
            const float hv0 = ws[HEADF + (base + i0) * Dx + d];
            const float hv1 = ws[HEADF + (base + i0 + 1) * Dx + d];
            const float pw0 = __expf(0.4f * hv0);
            const float pw1 = __expf(0.4f * hv1);
            const float2* ep2 = ((const float2*)(ws + ED)) + base * Dx + d;
            float s0 = 0.f, r0 = 0.f, s1 = 0.f, r1 = 0.f;
            if (st1 > st0) {
                const int j = vlist[st0];
                float2 v = ep2[j * Dx];
                float u0 = fmaf(v.x, pw0, 1.0f);
                float e0 = __expf(-10.0f * __builtin_amdgcn_rcpf(u0));
                s0 += e0; r0 = fmaf(e0, v.y, r0);
            }
            #pragma unroll 8
            for (int t = st1; t < cnt; ++t) {
                const int j = vlist[t];
                float2 v = ep2[j * Dx];
                float u0 = fmaf(v.x, pw0, 1.0f);
                float u1 = fmaf(v.x, pw1, 1.0f);
                float e0 = __expf(-10.0f * __builtin_amdgcn_rcpf(u0));
                float e1 = __expf(-10.0f * __builtin_amdgcn_rcpf(u1));
                s0 += e0; r0 = fmaf(e0, v.y, r0);
                s1 += e1; r1 = fmaf(e1, v.y, r1);
            }
            const float den0 = s0 + (s0 == 0.f ? 1.f : 0.f) + 1e-20f;
            const float den1 = s1 + (s1 == 0.f ? 1.f : 0.f) + 1e-20f;
            const float a0 = r0 / den0, a1 = r1 / den1;
            st_wt_f32(ws + ATTNF + (base + i0) * Dx + d,     a0);
            st_wt_f32(ws + ATTNF + (base + i0 + 1) * Dx + d, a1);
            st_wt_u16(U + ATB + (base + i0) * 320 + d,     f2bf(a0));
            st_wt_u16(U + ATB + (base + i0 + 1) * 320 + d, f2bf(a1));
        } else if (mv0 | mv1) {
            const int cnt = s_cnt;
            const int ia  = mv0 ? i0 : (i0 + 1);
            const int sta = mv0 ? s_st0 : s_st1;
            const float hv = ws[HEADF + (base + ia) * Dx + d];
            const float pw = __expf(0.4f * hv);
            const float2* ep2 = ((const float2*)(ws + ED)) + base * Dx + d;
            float s = 0.f, r = 0.f;
            #pragma unroll 8
            for (int t = sta; t < cnt; ++t) {
                const int j = vlist[t];
                float2 v = ep2[j * Dx];
                float u0 = fmaf(v.x, pw, 1.0f);
                float e  = __expf(-10.0f * __builtin_amdgcn_rcpf(u0));
                s += e; r = fmaf(e, v.y, r);
            }
            const float den = s + (s == 0.f ? 1.f : 0.f) + 1e-20f;
            const float a = r / den;
            st_wt_f32(ws + ATTNF + (base + ia) * Dx + d, a);
            st_wt_u16(U + ATB + (base + ia) * 320 + d, f2bf(a));
        }
    }
    gbar(ws, 1, 512);

    // ---- mm3: gate = sigmoid(rep@Wf1^T + attn@Wf2^T + bf); blend; mask ----
    if (blk < 320 && tid < 256) {
        const int w = tid >> 6, l = tid & 63;
        const int mt = blk / 5, nt = blk % 5;
        const int m0 = mt * 16, lm = l & 15, koff = (l >> 4) * 8;
        const int nrow = nt * 64 + w * 16 + lm;          // 0..319
        const unsigned short* a1p = U + REPB + (m0 + lm) * 320 + koff;
        const unsigned short* a2p = U + ATB  + (m0 + lm) * 320 + koff;
        const unsigned short* b1p = U + WPF1 + nrow * 320 + koff;
        const unsigned short* b2p = U + WPF2 + nrow * 320 + koff;
        f32x4 acc = {0.f, 0.f, 0.f, 0.f};
        #pragma unroll
        for (int ks = 0; ks < 10; ++ks) {
            short8 a = *(const short8*)(a1p + ks * 32);
            short8 b = *(const short8*)(b1p + ks * 32);
            acc = __builtin_amdgcn_mfma_f32_16x16x32_bf16(a, b, acc, 0, 0, 0);
        }
        #pragma unroll
        for (int ks = 0; ks < 10; ++ks) {
            short8 a = *(const short8*)(a2p + ks * 32);
            short8 b = *(const short8*)(b2p + ks * 32);
            acc = __builtin_amdgcn_mfma_f32_16x16x32_bf16(a, b, acc, 0, 0, 0);
        }
        if (nrow < 300) {
            float bb = ldf(bfv, nrow, isbf);
            #pragma unroll
            for (int r = 0; r < 4; ++r) {
                int mg = m0 + (l >> 4) * 4 + r;
                float res = 0.f;
                if (mask[mg]) {
                    float gp = acc[r] + bb;
                    float gate = 1.0f / (1.0f + __expf(-gp));
                    float rv = ws[REPF  + mg * 300 + nrow];
                    float av = ws[ATTNF + mg * 300 + nrow];
                    res = gate * rv + (1.0f - gate) * av;
                }
                if (isbf) ((__hip_bfloat16*)outv)[mg * 300 + nrow] = __float2bfloat16(res);
                else      ((float*)outv)[mg * 300 + nrow] = res;
            }
        }
    }
}

extern "C" void kernel_launch(void* const* d_in, const int* in_sizes, int n_in,
                              void* d_out, int out_size, void* d_ws, size_t ws_size,
                              hipStream_t stream) {
    const void* X   = d_in[0];
    const int*  msk = (const int*)d_in[1];
    const void* Wfc = d_in[2];
    const void* bfc = d_in[3];
    const void* W1  = d_in[4];
    const void* W2  = d_in[5];
    const void* b1  = d_in[6];
    const void* Wf1 = d_in[7];
    const void* Wf2 = d_in[8];
    const void* bfv = d_in[9];
    float* ws = (float*)d_ws;

    // zero the barrier state (2 barriers x 8 KB)
    hipMemsetAsync((char*)d_ws + (size_t)SYNC_FOFF * sizeof(float), 0, 16384, stream);

    hipLaunchKernelGGL(k_a, dim3(640), dim3(320), 0, stream,
                       X, Wfc, bfc, W1, W2, b1, Wf1, Wf2, ws);
    hipLaunchKernelGGL(k_b, dim3(512), dim3(320), 0, stream,
                       msk, Wfc, bfv, ws, d_out);
}

// Round 8
// 119.538 us; speedup vs baseline: 3.9858x; 1.0643x over previous
//
#include <hip/hip_runtime.h>
#include <hip/hip_bf16.h>

#define Dx 300

// float-offsets into ws. All inter-block intermediates written with sc0/sc1
// write-through (coherence point); consumers first-touch after their flag.
#define ED     0             // float2 [1024][300] {exd, rep}
#define HEADF  614400        // f32 [1024][300]
#define ATTNF  921600        // f32 [1024][300]
#define U_BASE 1228800       // ushort region (float offset)
#define REPB   0             // bf16 [1024][320]
#define ATB    327680        // bf16 [1024][320]
#define SYNC_FOFF 2000000    // flag state (memset before launch)

#define AG __HIP_MEMORY_SCOPE_AGENT

typedef __attribute__((ext_vector_type(8))) short short8;
typedef __attribute__((ext_vector_type(4))) float f32x4;

union S8 { unsigned int u[4]; unsigned short s[8]; short8 v; };

__device__ __forceinline__ float bf2f(unsigned short u) {
    union { unsigned int i; float f; } v; v.i = ((unsigned int)u) << 16; return v.f;
}
__device__ __forceinline__ unsigned short f2bf(float x) {   // round-half-up
    union { float f; unsigned int i; } u; u.f = x;
    return (unsigned short)((u.i + 0x8000u) >> 16);
}
__device__ __forceinline__ float ldf(const void* p, int idx, int isbf) {
    return isbf ? bf2f(((const unsigned short*)p)[idx]) : ((const float*)p)[idx];
}

// write-through stores (visible at coherence point once vmcnt acks)
__device__ __forceinline__ void st_wt_f32(float* p, float v) {
    asm volatile("global_store_dword %0, %1, off sc0 sc1"
                 :: "v"(p), "v"(v) : "memory");
}
__device__ __forceinline__ void st_wt_u16(unsigned short* p, unsigned short v) {
    unsigned int vv = v;
    asm volatile("global_store_short %0, %1, off sc0 sc1"
                 :: "v"(p), "v"(vv) : "memory");
}

__device__ __forceinline__ void load8f(const float* rowp, int kb, int kmax,
                                       int valid, float* x) {
    if (valid && kb + 8 <= kmax) {
        float4 a = *(const float4*)(rowp + kb);
        float4 b = *(const float4*)(rowp + kb + 4);
        x[0]=a.x; x[1]=a.y; x[2]=a.z; x[3]=a.w;
        x[4]=b.x; x[5]=b.y; x[6]=b.z; x[7]=b.w;
    } else {
        #pragma unroll
        for (int j = 0; j < 8; ++j) {
            int k = kb + j;
            x[j] = (valid && k < kmax) ? rowp[k] : 0.f;
        }
    }
}
__device__ __forceinline__ short8 pack8(const float* x) {
    S8 H;
    #pragma unroll
    for (int p = 0; p < 4; ++p) {
        union { float f; unsigned int i; } a, b;
        a.f = x[2*p]; b.f = x[2*p+1];
        H.u[p] = ((a.i + 0x8000u) >> 16) | ((b.i + 0x8000u) & 0xFFFF0000u);
    }
    return H.v;
}
__device__ __forceinline__ short8 load8bf(const unsigned short* rowp, int kb,
                                          int kmax, int valid) {
    S8 R;
    if (valid && kb + 8 <= kmax) {
        ushort4 a = *(const ushort4*)(rowp + kb);
        ushort4 b = *(const ushort4*)(rowp + kb + 4);
        R.s[0]=a.x; R.s[1]=a.y; R.s[2]=a.z; R.s[3]=a.w;
        R.s[4]=b.x; R.s[5]=b.y; R.s[6]=b.z; R.s[7]=b.w;
    } else {
        #pragma unroll
        for (int j = 0; j < 8; ++j) {
            int k = kb + j;
            R.s[j] = (valid && k < kmax) ? rowp[k] : (unsigned short)0;
        }
    }
    return R.v;
}
__device__ __forceinline__ short8 loadB(const void* W, int row, int kb, int isbf,
                                        int valid) {
    if (isbf) return load8bf((const unsigned short*)W + row * 300, kb, 300, valid);
    float t[8];
    load8f((const float*)W + row * 300, kb, 300, valid, t);
    return pack8(t);
}

__device__ __forceinline__ int xcd_id() {
    int x;
    asm volatile("s_getreg_b32 %0, hwreg(HW_REG_XCC_ID)" : "=s"(x));
    return x & 7;
}
// relaxed spin until *p >= target; bounded (lost block => visible fail)
__device__ __forceinline__ void spin_ge(int* p, int target) {
    int t = 0;
    while (__hip_atomic_load(p, __ATOMIC_RELAXED, AG) < target) {
        __builtin_amdgcn_s_sleep(2);
        if (++t > 300000) break;
    }
    asm volatile("" ::: "memory");
}

// SYNC slot layout (int index, 256 B apart): cnt1[mt]=mt*64 (mm1 tiles, tgt 5)
// cnt2[b]=(64+b)*64 (mm2 units/batch, tgt 160); fb[b][x]=(68+b*8+x)*64;
// cnt3[mt]=(100+mt)*64 (attn pairs/tile, tgt 8).

// ---------------------------------------------------------------------------
// Fused DiSA, flag-chained (no grid barriers): mm1 -> cnt1 -> mm2 -> fb ->
// attn -> cnt3 -> mm3.  grid 512 x 320 (co-resident: 5 waves/block, <=6
// blocks/CU => capacity 1536 >= 512).
// ---------------------------------------------------------------------------
__global__ __launch_bounds__(320, 4) void k_fused(
        const void* __restrict__ Xv, const int* __restrict__ mask,
        const void* __restrict__ Wfc, const void* __restrict__ bfc,
        const void* __restrict__ W1,  const void* __restrict__ W2,
        const void* __restrict__ b1v, const void* __restrict__ Wf1,
        const void* __restrict__ Wf2, const void* __restrict__ bfv,
        float* __restrict__ ws, void* __restrict__ outv) {
    __shared__ int s_isbf;
    __shared__ unsigned short vlist[256];
    __shared__ int s_cnt, s_st0, s_st1;

    const int tid = threadIdx.x;
    const int blk = blockIdx.x;
    // wave-parallel bf16 detect (1 load latency, not 64)
    if (tid < 64) {
        float v = bf2f(((const unsigned short*)Wfc)[tid]);
        int ok = fabsf(v) < 1.0f;
        unsigned long long bal = __ballot(ok);
        if (tid == 0) s_isbf = (bal == ~0ull) ? 1 : 0;
    }
    __syncthreads();
    const int isbf = s_isbf;
    unsigned short* U = (unsigned short*)(ws + U_BASE);
    int* S = (int*)(ws + SYNC_FOFF);
    const int xid = xcd_id();

    // ---- Phase 1: mm1  rep = elu(X@Wfc^T + bfc)  (blocks 0..319) ----
    if (blk < 320 && tid < 256) {
        const int w = tid >> 6, l = tid & 63;
        const int mt = blk / 5, nt = blk % 5;
        const int m0 = mt * 16, lm = l & 15, koff = (l >> 4) * 8;
        const int nrow = nt * 64 + w * 16 + lm;          // 0..319
        const int bval = nrow < 300;
        const int ncl = bval ? nrow : 0;
        f32x4 acc = {0.f, 0.f, 0.f, 0.f};
        if (isbf) {
            const unsigned short* Xp = (const unsigned short*)Xv + (m0 + lm) * 300;
            #pragma unroll
            for (int ks = 0; ks < 10; ++ks) {
                short8 a = load8bf(Xp, ks*32 + koff, 300, 1);
                short8 b = loadB(Wfc, ncl, ks*32 + koff, 1, bval);
                acc = __builtin_amdgcn_mfma_f32_16x16x32_bf16(a, b, acc, 0, 0, 0);
            }
        } else {
            const float* Xp = (const float*)Xv + (m0 + lm) * 300;
            #pragma unroll
            for (int ks = 0; ks < 10; ++ks) {
                float t[8]; load8f(Xp, ks*32 + koff, 300, 1, t);
                short8 a = pack8(t);
                short8 b = loadB(Wfc, ncl, ks*32 + koff, 0, bval);
                acc = __builtin_amdgcn_mfma_f32_16x16x32_bf16(a, b, acc, 0, 0, 0);
            }
        }
        if (bval) {
            float bb = ldf(bfc, nrow, isbf);
            #pragma unroll
            for (int r = 0; r < 4; ++r) {
                int mg = m0 + (l >> 4) * 4 + r;
                float v = acc[r] + bb;
                v = v > 0.f ? v : (__expf(v) - 1.f);
                st_wt_f32(ws + ED + (mg * 300 + nrow) * 2 + 1, v);  // ed.y = rep
                st_wt_u16(U + REPB + mg * 320 + nrow, f2bf(v));
            }
        } else {
            #pragma unroll
            for (int r = 0; r < 4; ++r) {
                int mg = m0 + (l >> 4) * 4 + r;
                st_wt_u16(U + REPB + mg * 320 + nrow, 0);
            }
        }
    }
    __syncthreads();                                // drains all waves' vmcnt
    if (blk < 320 && tid == 0)
        __hip_atomic_fetch_add(S + (blk / 5) * 64, 1, __ATOMIC_RELAXED, AG);

    // ---- Phase 2: mm2  dep/head = rep @ {W1,W2}^T (raw B).  640 units:
    //      u = blk (all); u = 512+(blk-320) for blocks 320..447. ----
    {
        int u0 = blk;
        int u1 = (blk >= 320 && blk < 448) ? 512 + (blk - 320) : -1;
        for (int q = 0; q < 2; ++q) {
            const int u = (q == 0) ? u0 : u1;
            if (u < 0) break;
            const int mt = u / 10, nt = u % 10;
            if (tid == 0) spin_ge(S + mt * 64, 5);
            __syncthreads();
            if (tid < 256) {
                const int w = tid >> 6, l = tid & 63;
                const int m0 = mt * 16, lm = l & 15, koff = (l >> 4) * 8;
                const int ng = nt * 64 + w * 16 + lm;        // 0..639
                const int wsel = ng < 320;
                const int wrow = wsel ? ng : ng - 320;
                const int bval = wrow < 300;
                const int ncl = bval ? wrow : 0;
                const void* Wsel = wsel ? W1 : W2;
                const unsigned short* ap = U + REPB + (m0 + lm) * 320 + koff;
                f32x4 acc = {0.f, 0.f, 0.f, 0.f};
                #pragma unroll
                for (int ks = 0; ks < 10; ++ks) {
                    short8 a = *(const short8*)(ap + ks * 32);
                    short8 b = loadB(Wsel, ncl, ks*32 + koff, isbf, bval);
                    acc = __builtin_amdgcn_mfma_f32_16x16x32_bf16(a, b, acc, 0, 0, 0);
                }
                if (ng < 300) {
                    float bb = ldf(b1v, ng, isbf);
                    #pragma unroll
                    for (int r = 0; r < 4; ++r) {
                        int mg = m0 + (l >> 4) * 4 + r;
                        st_wt_f32(ws + ED + (mg * 300 + ng) * 2,
                                  __expf(0.4f * (acc[r] + bb)));   // ed.x
                    }
                } else if (ng >= 320 && ng < 620) {
                    #pragma unroll
                    for (int r = 0; r < 4; ++r) {
                        int mg = m0 + (l >> 4) * 4 + r;
                        st_wt_f32(ws + HEADF + mg * 300 + (ng - 320), acc[r]);
                    }
                }
            }
            __syncthreads();                        // drain before flag
            if (tid == 0) {
                const int bb = mt >> 4;
                int old = __hip_atomic_fetch_add(S + (64 + bb) * 64, 1,
                                                 __ATOMIC_RELAXED, AG);
                if (old == 159) {                   // last mm2 unit of batch
                    #pragma unroll
                    for (int x = 0; x < 8; ++x)
                        __hip_atomic_store(S + (68 + bb * 8 + x) * 64, 1,
                                           __ATOMIC_RELAXED, AG);
                }
            }
        }
    }

    // ---- Phase 3: attn (512 i-pair units, u = blk); mask-skip ----
    const int b = blk >> 7;
    const int tile = blk & 127;
    const int uu = tile >> 1;
    const int i0 = (tile & 1) ? (254 - 2 * uu) : (2 * uu);
    const int base = b * 256;
    if (tid == 0) spin_ge(S + (68 + b * 8 + xid) * 64, 1);
    __syncthreads();
    {
        const int mv0 = mask[base + i0] != 0;
        const int mv1 = mask[base + i0 + 1] != 0;
        if ((mv0 | mv1) && tid < 64) {
            int basec = 0, st0 = 0, st1 = 0;
            #pragma unroll
            for (int c = 0; c < 4; ++c) {
                const int j = c * 64 + tid;
                const int mv = mask[base + j] != 0;
                unsigned long long bal = __ballot(mv);
                int pos = basec + __popcll(bal & ((1ull << tid) - 1ull));
                if (mv) vlist[pos] = (unsigned short)j;
                if (tid == 0) {
                    int lim0 = i0 - c * 64;
                    if (lim0 >= 0)
                        st0 += __popcll(bal & (lim0 >= 63 ? ~0ull : ((2ull << lim0) - 1ull)));
                    int lim1 = i0 + 1 - c * 64;
                    if (lim1 >= 0)
                        st1 += __popcll(bal & (lim1 >= 63 ? ~0ull : ((2ull << lim1) - 1ull)));
                }
                basec += __popcll(bal);
            }
            if (tid == 0) { s_cnt = basec; s_st0 = st0; s_st1 = st1; }
        }
        __syncthreads();
        const int d = tid;
        if (d >= 300) {
            st_wt_u16(U + ATB + (base + i0) * 320 + d, 0);
            st_wt_u16(U + ATB + (base + i0 + 1) * 320 + d, 0);
        } else if (mv0 & mv1) {
            const int cnt = s_cnt, st0 = s_st0, st1 = s_st1;
            const float hv0 = ws[HEADF + (base + i0) * Dx + d];
            const float hv1 = ws[HEADF + (base + i0 + 1) * Dx + d];
            const float pw0 = __expf(0.4f * hv0);
            const float pw1 = __expf(0.4f * hv1);
            const float2* ep2 = ((const float2*)(ws + ED)) + base * Dx + d;
            float s0 = 0.f, r0 = 0.f, s1 = 0.f, r1 = 0.f;
            if (st1 > st0) {
                const int j = vlist[st0];
                float2 v = ep2[j * Dx];
                float u0 = fmaf(v.x, pw0, 1.0f);
                float e0 = __expf(-10.0f * __builtin_amdgcn_rcpf(u0));
                s0 += e0; r0 = fmaf(e0, v.y, r0);
            }
            #pragma unroll 8
            for (int t = st1; t < cnt; ++t) {
                const int j = vlist[t];
                float2 v = ep2[j * Dx];
                float u0 = fmaf(v.x, pw0, 1.0f);
                float u1 = fmaf(v.x, pw1, 1.0f);
                float e0 = __expf(-10.0f * __builtin_amdgcn_rcpf(u0));
                float e1 = __expf(-10.0f * __builtin_amdgcn_rcpf(u1));
                s0 += e0; r0 = fmaf(e0, v.y, r0);
                s1 += e1; r1 = fmaf(e1, v.y, r1);
            }
            const float den0 = s0 + (s0 == 0.f ? 1.f : 0.f) + 1e-20f;
            const float den1 = s1 + (s1 == 0.f ? 1.f : 0.f) + 1e-20f;
            const float a0 = r0 / den0, a1 = r1 / den1;
            st_wt_f32(ws + ATTNF + (base + i0) * Dx + d,     a0);
            st_wt_f32(ws + ATTNF + (base + i0 + 1) * Dx + d, a1);
            st_wt_u16(U + ATB + (base + i0) * 320 + d,     f2bf(a0));
            st_wt_u16(U + ATB + (base + i0 + 1) * 320 + d, f2bf(a1));
        } else if (mv0 | mv1) {
            const int cnt = s_cnt;
            const int ia  = mv0 ? i0 : (i0 + 1);
            const int sta = mv0 ? s_st0 : s_st1;
            const float hv = ws[HEADF + (base + ia) * Dx + d];
            const float pw = __expf(0.4f * hv);
            const float2* ep2 = ((const float2*)(ws + ED)) + base * Dx + d;
            float s = 0.f, r = 0.f;
            #pragma unroll 8
            for (int t = sta; t < cnt; ++t) {
                const int j = vlist[t];
                float2 v = ep2[j * Dx];
                float u0 = fmaf(v.x, pw, 1.0f);
                float e  = __expf(-10.0f * __builtin_amdgcn_rcpf(u0));
                s += e; r = fmaf(e, v.y, r);
            }
            const float den = s + (s == 0.f ? 1.f : 0.f) + 1e-20f;
            const float a = r / den;
            st_wt_f32(ws + ATTNF + (base + ia) * Dx + d, a);
            st_wt_u16(U + ATB + (base + ia) * 320 + d, f2bf(a));
        }
    }
    __syncthreads();                                // drain before flag
    if (tid == 0)
        __hip_atomic_fetch_add(S + (100 + ((base + i0) >> 4)) * 64, 1,
                               __ATOMIC_RELAXED, AG);

    // ---- Phase 4: mm3 (320 units on blocks 192..511) ----
    if (blk >= 192) {
        const int u = blk - 192;
        const int mt3 = u / 5, nt3 = u % 5;
        if (tid == 0) spin_ge(S + (100 + mt3) * 64, 8);
        __syncthreads();
        if (tid < 256) {
            const int w = tid >> 6, l = tid & 63;
            const int m0 = mt3 * 16, lm = l & 15, koff = (l >> 4) * 8;
            const int nrow = nt3 * 64 + w * 16 + lm;     // 0..319
            const int bval = nrow < 300;
            const int ncl = bval ? nrow : 0;
            const unsigned short* a1p = U + REPB + (m0 + lm) * 320 + koff;
            const unsigned short* a2p = U + ATB  + (m0 + lm) * 320 + koff;
            f32x4 acc = {0.f, 0.f, 0.f, 0.f};
            #pragma unroll
            for (int ks = 0; ks < 10; ++ks) {
                short8 a = *(const short8*)(a1p + ks * 32);
                short8 bB = loadB(Wf1, ncl, ks*32 + koff, isbf, bval);
                acc = __builtin_amdgcn_mfma_f32_16x16x32_bf16(a, bB, acc, 0, 0, 0);
            }
            #pragma unroll
            for (int ks = 0; ks < 10; ++ks) {
                short8 a = *(const short8*)(a2p + ks * 32);
                short8 bB = loadB(Wf2, ncl, ks*32 + koff, isbf, bval);
                acc = __builtin_amdgcn_mfma_f32_16x16x32_bf16(a, bB, acc, 0, 0, 0);
            }
            if (bval) {
                float bb = ldf(bfv, nrow, isbf);
                #pragma unroll
                for (int r = 0; r < 4; ++r) {
                    int mg = m0 + (l >> 4) * 4 + r;
                    float res = 0.f;
                    if (mask[mg]) {
                        float gp = acc[r] + bb;
                        float gate = 1.0f / (1.0f + __expf(-gp));
                        float rv = ws[ED + (mg * 300 + nrow) * 2 + 1];
                        float av = ws[ATTNF + mg * 300 + nrow];
                        res = gate * rv + (1.0f - gate) * av;
                    }
                    if (isbf) ((__hip_bfloat16*)outv)[mg * 300 + nrow] = __float2bfloat16(res);
                    else      ((float*)outv)[mg * 300 + nrow] = res;
                }
            }
        }
    }
}

extern "C" void kernel_launch(void* const* d_in, const int* in_sizes, int n_in,
                              void* d_out, int out_size, void* d_ws, size_t ws_size,
                              hipStream_t stream) {
    const void* X   = d_in[0];
    const int*  msk = (const int*)d_in[1];
    const void* Wfc = d_in[2];
    const void* bfc = d_in[3];
    const void* W1  = d_in[4];
    const void* W2  = d_in[5];
    const void* b1  = d_in[6];
    const void* Wf1 = d_in[7];
    const void* Wf2 = d_in[8];
    const void* bfv = d_in[9];
    float* ws = (float*)d_ws;

    // zero the flag state (cnt1[64] + cnt2[4] + fb[32] + cnt3[64] slots x 256B)
    hipMemsetAsync((char*)d_ws + (size_t)SYNC_FOFF * sizeof(float), 0, 49152, stream);

    hipLaunchKernelGGL(k_fused, dim3(512), dim3(320), 0, stream,
                       X, msk, Wfc, bfc, W1, W2, b1, Wf1, Wf2, bfv, ws, d_out);
}